// Round 6
// baseline (392.966 us; speedup 1.0000x reference)
//
#include <hip/hip_runtime.h>
#include <hip/hip_bf16.h>
#include <cstddef>

// Problem constants (static shapes from the reference)
#define LQ   17821
#define BS   2
#define MTOK (BS * LQ)       // 35642 token rows
#define CDIM 256
#define NHD  8
#define DHEAD 32
#define DFFN 1024

typedef short bf16x4 __attribute__((ext_vector_type(4)));
typedef short bf16x8 __attribute__((ext_vector_type(8)));
typedef float f32x4  __attribute__((ext_vector_type(4)));
typedef float f32x2  __attribute__((ext_vector_type(2)));

typedef const __attribute__((address_space(1))) unsigned char gcu8;
typedef __attribute__((address_space(3))) unsigned char lu8;

// async global->LDS, 16B per lane, dest = wave-uniform base + lane*16 (linear)
__device__ __forceinline__ void gload16(const void* g, void* l) {
    __builtin_amdgcn_global_load_lds((gcu8*)g, (lu8*)l, 16, 0, 0);
}

// ---------------------------------------------------------------------------
// fp8 e4m3 (OCP) encode/decode helpers — HW path with SW fallback
// ---------------------------------------------------------------------------
__device__ __forceinline__ unsigned char fp8_enc(float f) {
#if __has_builtin(__builtin_amdgcn_cvt_pk_fp8_f32)
    return (unsigned char)(__builtin_amdgcn_cvt_pk_fp8_f32(f, f, 0, false) & 0xff);
#else
    unsigned s = (__float_as_uint(f) >> 31) << 7;
    float af = fabsf(f);
    if (af < 0.0078125f) return (unsigned char)s;   // flush tiny/subnormal
    af = fminf(af, 448.f);
    unsigned b = __float_as_uint(af);
    int e = (int)(b >> 23) - 127 + 7;
    unsigned m = (b >> 20) & 7;
    if (b & 0x80000) { m++; if (m == 8) { m = 0; e++; } }
    if (e < 1) return (unsigned char)s;
    if (e > 15) { e = 15; m = 6; }
    return (unsigned char)(s | ((unsigned)e << 3) | m);
#endif
}

__device__ __forceinline__ float fp8_dec_byte(unsigned x) {
    unsigned s = (x >> 7) & 1, e = (x >> 3) & 15, m = x & 7;
    float v = e ? __uint_as_float(((e + 120u) << 23) | (m << 20))
                : (float)m * 0.001953125f;
    return s ? -v : v;
}

// Decode 2 fp8 bytes (low pair HI=false, high pair HI=true) of a dword.
template <bool HI>
__device__ __forceinline__ f32x2 fp8_dec2(unsigned d) {
#if __has_builtin(__builtin_amdgcn_cvt_pk_f32_fp8)
    return __builtin_amdgcn_cvt_pk_f32_fp8(d, HI);
#else
    f32x2 r;
    r[0] = fp8_dec_byte((d >> (HI ? 16 : 0)) & 0xff);
    r[1] = fp8_dec_byte((d >> (HI ? 24 : 8)) & 0xff);
    return r;
#endif
}

__device__ __forceinline__ ushort bfpack(float f) {
    __hip_bfloat16 h = (__hip_bfloat16)f;
    return *(ushort*)&h;
}

// Stage 8 fp8 bytes (uint2) -> 8 bf16 in LDS
__device__ __forceinline__ void stage_a8(short* p, uint2 d) {
    const f32x2 p0 = fp8_dec2<false>(d.x), p1 = fp8_dec2<true>(d.x);
    const f32x2 p2 = fp8_dec2<false>(d.y), p3 = fp8_dec2<true>(d.y);
    bf16x4 lo, hi;
    lo[0] = (short)bfpack(p0[0]); lo[1] = (short)bfpack(p0[1]);
    lo[2] = (short)bfpack(p1[0]); lo[3] = (short)bfpack(p1[1]);
    hi[0] = (short)bfpack(p2[0]); hi[1] = (short)bfpack(p2[1]);
    hi[2] = (short)bfpack(p3[0]); hi[3] = (short)bfpack(p3[1]);
    ((bf16x4*)p)[0] = lo;
    ((bf16x4*)p)[1] = hi;
}

// ---------------------------------------------------------------------------
// Batched fp32 -> bf16 weight cast; optional per-column scale (norm folding)
// ---------------------------------------------------------------------------
struct CastJobs {
    const float* src[7];
    __hip_bfloat16* dst[7];
    const float* colw[7];   // if non-null: dst = src * colw[i & 255]
    int n[7];
};

__global__ __launch_bounds__(256)
void cast_all(CastJobs j) {
    const int seg = blockIdx.y;
    const int i = blockIdx.x * 256 + threadIdx.x;
    if (i < j.n[seg]) {
        float v = j.src[seg][i];
        if (j.colw[seg]) v *= j.colw[seg][i & 255];
        j.dst[seg][i] = (__hip_bfloat16)v;
    }
}

// ---------------------------------------------------------------------------
// RMSNorm, wave-per-token (64 lanes x float4 = 256 ch), 4 tokens/block.
// ---------------------------------------------------------------------------
template <bool ADD_POS>
__global__ __launch_bounds__(256)
void rmsnorm_kernel(const float* __restrict__ x, const float* __restrict__ pos,
                    const float* __restrict__ w,
                    __hip_bfloat16* __restrict__ outN, __hip_bfloat16* __restrict__ outQ) {
    const int tok = blockIdx.x * 4 + (threadIdx.x >> 6);
    if (tok >= MTOK) return;
    const int lane = threadIdx.x & 63;
    const size_t base = (size_t)tok * CDIM + lane * 4;
    const float4 v = *(const float4*)&x[base];
    float ss = v.x * v.x + v.y * v.y + v.z * v.z + v.w * v.w;
#pragma unroll
    for (int m = 1; m < 64; m <<= 1) ss += __shfl_xor(ss, m, 64);
    const float r = rsqrtf(ss * (1.0f / CDIM) + 1e-6f);
    const float4 wv = *(const float4*)&w[lane * 4];
    const float n0 = v.x * r * wv.x, n1 = v.y * r * wv.y;
    const float n2 = v.z * r * wv.z, n3 = v.w * r * wv.w;
    ushort4 o;
    o.x = bfpack(n0); o.y = bfpack(n1); o.z = bfpack(n2); o.w = bfpack(n3);
    *(ushort4*)&outN[base] = o;
    if (ADD_POS) {
        const float4 p = *(const float4*)&pos[base];
        ushort4 q;
        q.x = bfpack(n0 + p.x); q.y = bfpack(n1 + p.y);
        q.z = bfpack(n2 + p.z); q.w = bfpack(n3 + p.w);
        *(ushort4*)&outQ[base] = q;
    }
}

// ---------------------------------------------------------------------------
// Row RMS scale only: r[m] = rsqrt(mean(x^2)+eps), x bf16. 4 tokens/block.
// ---------------------------------------------------------------------------
__global__ __launch_bounds__(256)
void rowrms_kernel(const __hip_bfloat16* __restrict__ x, float* __restrict__ r) {
    const int tok = blockIdx.x * 4 + (threadIdx.x >> 6);
    if (tok >= MTOK) return;
    const int lane = threadIdx.x & 63;
    const ushort4 u = *(const ushort4*)&x[(size_t)tok * CDIM + lane * 4];
    const float v0 = __uint_as_float((unsigned)u.x << 16);
    const float v1 = __uint_as_float((unsigned)u.y << 16);
    const float v2 = __uint_as_float((unsigned)u.z << 16);
    const float v3 = __uint_as_float((unsigned)u.w << 16);
    float ss = v0 * v0 + v1 * v1 + v2 * v2 + v3 * v3;
#pragma unroll
    for (int m = 1; m < 64; m <<= 1) ss += __shfl_xor(ss, m, 64);
    if (lane == 0) r[tok] = rsqrtf(ss * (1.0f / CDIM) + 1e-6f);
}

// ---------------------------------------------------------------------------
// bf16 MFMA GEMM: C[M,N] = A[M,K] @ W[N,K]^T (+ epilogues), fp32 accumulate.
// 128x128 block tile, templated BK, 4 waves (2x2), wave = 4x4 of 16x16x32.
// Flat grid, n-fastest swizzle: m0 = bid/nsw, n0 = bid%nsw (L2 A-reuse).
// A8: A operand stored fp8 e4m3, decoded to bf16 during LDS staging.
// MODE 0: out = acc + bias1
// MODE 1: value layout write (b, h, q, c), fp8 e4m3
// MODE 2: out = resid_f32 + ls * (acc + bias1)
// MODE 4: out = acc + concat(bias1[0:256], bias2[0:128])[n]   (proj N=384)
// MODE 5: out = resid_bf16 + ls * (acc + bias1), f32 out
// ---------------------------------------------------------------------------
#define GBM 128
#define GBN 128

template <int MODE, int BKT, typename OUTT, bool A8 = false>
__global__ __launch_bounds__(256, 2)
void mfma_gemm(const void* __restrict__ Av,
               const __hip_bfloat16* __restrict__ B1, const float* __restrict__ bias1,
               const float* __restrict__ bias2,
               const float* __restrict__ resid, const __hip_bfloat16* __restrict__ residb,
               const float* __restrict__ ls,
               OUTT* __restrict__ out, int M, int N, int K, int nsw) {
    constexpr int LDKT = BKT + 8;        // +16B pad: 2-way bank alias (free)
    constexpr int CH = BKT / 16;         // staging chunks per thread per matrix
    constexpr int CPR = BKT / 8;         // 8-elem chunks per row

    __shared__ short As[GBM * LDKT];
    __shared__ short Bs[GBN * LDKT];

    const __hip_bfloat16* A = (const __hip_bfloat16*)Av;
    const unsigned char* A8p = (const unsigned char*)Av;

    const int tid = threadIdx.x;
    const int bid = blockIdx.x;
    const int m0 = (bid / nsw) * GBM;
    const int n0 = (bid % nsw) * GBN;
    const int wave = tid >> 6;
    const int lane = tid & 63;
    const int wm = (wave >> 1) * 64;
    const int wn = (wave & 1) * 64;
    const int fr = lane & 15;   // col of C
    const int fq = lane >> 4;   // quad: k = fq*8+j ; C row = fq*4+r

    f32x4 acc[4][4] = {};

    int srow[CH], skc[CH];
#pragma unroll
    for (int cc = 0; cc < CH; ++cc) {
        const int g = tid + cc * 256;
        srow[cc] = g / CPR;
        skc[cc] = (g % CPR) * 8;
    }
    const uint4 zero4 = make_uint4(0, 0, 0, 0);
    const uint2 zero2 = make_uint2(0, 0);

    uint4 ra[CH], rb[CH];
    uint2 ra8[A8 ? CH : 1];
#pragma unroll
    for (int cc = 0; cc < CH; ++cc) {
        const int gm = m0 + srow[cc];
        if constexpr (A8)
            ra8[cc] = (gm < M) ? *(const uint2*)&A8p[(size_t)gm * K + skc[cc]] : zero2;
        else
            ra[cc] = (gm < M) ? *(const uint4*)&A[(size_t)gm * K + skc[cc]] : zero4;
        rb[cc] = *(const uint4*)&B1[(size_t)(n0 + srow[cc]) * K + skc[cc]];
    }

    for (int k0 = 0; k0 < K; k0 += BKT) {
        __syncthreads();
#pragma unroll
        for (int cc = 0; cc < CH; ++cc) {
            short* pa = &As[srow[cc] * LDKT + skc[cc]];
            short* pb = &Bs[srow[cc] * LDKT + skc[cc]];
            if constexpr (A8) {
                stage_a8(pa, ra8[cc]);
            } else {
                union { uint4 u; bf16x4 h[2]; } cv;
                cv.u = ra[cc]; ((bf16x4*)pa)[0] = cv.h[0]; ((bf16x4*)pa)[1] = cv.h[1];
            }
            union { uint4 u; bf16x4 h[2]; } cv;
            cv.u = rb[cc]; ((bf16x4*)pb)[0] = cv.h[0]; ((bf16x4*)pb)[1] = cv.h[1];
        }
        __syncthreads();

        if (k0 + BKT < K) {
            const int kn = k0 + BKT;
#pragma unroll
            for (int cc = 0; cc < CH; ++cc) {
                const int gm = m0 + srow[cc];
                if constexpr (A8)
                    ra8[cc] = (gm < M) ? *(const uint2*)&A8p[(size_t)gm * K + kn + skc[cc]] : zero2;
                else
                    ra[cc] = (gm < M) ? *(const uint4*)&A[(size_t)gm * K + kn + skc[cc]] : zero4;
                rb[cc] = *(const uint4*)&B1[(size_t)(n0 + srow[cc]) * K + kn + skc[cc]];
            }
        }

#pragma unroll
        for (int kk = 0; kk < BKT; kk += 32) {
            const int kq = kk + fq * 8;
            bf16x8 af[4], bfr[4];
#pragma unroll
            for (int i = 0; i < 4; ++i)
                af[i] = *(const bf16x8*)&As[(wm + i * 16 + fr) * LDKT + kq];
#pragma unroll
            for (int j = 0; j < 4; ++j)
                bfr[j] = *(const bf16x8*)&Bs[(wn + j * 16 + fr) * LDKT + kq];
#pragma unroll
            for (int i = 0; i < 4; ++i)
#pragma unroll
                for (int j = 0; j < 4; ++j)
                    acc[i][j] = __builtin_amdgcn_mfma_f32_16x16x32_bf16(af[i], bfr[j], acc[i][j], 0, 0, 0);
        }
    }

#pragma unroll
    for (int i = 0; i < 4; ++i) {
#pragma unroll
        for (int r = 0; r < 4; ++r) {
            const int m = m0 + wm + i * 16 + fq * 4 + r;
            if (m >= M) continue;
#pragma unroll
            for (int j = 0; j < 4; ++j) {
                const int n = n0 + wn + j * 16 + fr;
                float v;
                if constexpr (MODE == 4)
                    v = acc[i][j][r] + ((n < 256) ? bias1[n] : bias2[n - 256]);
                else
                    v = acc[i][j][r] + bias1[n];
                if constexpr (MODE == 0 || MODE == 4) {
                    out[(size_t)m * N + n] = (OUTT)v;
                } else if constexpr (MODE == 1) {
                    const int b = (m >= LQ) ? 1 : 0;
                    const int qi = m - b * LQ;
                    const int h = n >> 5;
                    const int c = n & 31;
                    ((unsigned char*)out)[((size_t)(b * NHD + h) * LQ + qi) * DHEAD + c] = fp8_enc(v);
                } else if constexpr (MODE == 2) {
                    out[(size_t)m * N + n] =
                        (OUTT)(resid[(size_t)m * N + n] + ls[n] * v);
                } else {  // MODE 5: bf16 residual, f32 out
                    const float rx = __uint_as_float(
                        (unsigned)(*(const ushort*)&residb[(size_t)m * N + n]) << 16);
                    out[(size_t)m * N + n] = (OUTT)(rx + ls[n] * v);
                }
            }
        }
    }
}

// ---------------------------------------------------------------------------
// SwiGLU dual GEMM: h = silu(r[m]*(x@W1'^T)+b1) * (r[m]*(x@W2'^T)+b2)
// 128x64 block tile, BK=64, DOUBLE-BUFFERED global_load_lds staging (m97
// pattern): stage(buf[nxt], t+1) issued BEFORE compute(buf[cur]) so the
// loads fly under the MFMA phase; single barrier/k-step (implicit vmcnt(0)
// drain covers the loads issued one iteration earlier).
// XOR-swizzled content (round-5, conflict-free verified): linear dest,
// inverse-swizzled global source, same XOR on ds_read address.
// LDS 64KB -> 2 blocks/CU. h written fp8 e4m3.
// ---------------------------------------------------------------------------
__global__ __launch_bounds__(256, 2)
void mfma_swiglu(const __hip_bfloat16* __restrict__ A,
                 const __hip_bfloat16* __restrict__ B1, const float* __restrict__ bias1,
                 const __hip_bfloat16* __restrict__ B2, const float* __restrict__ bias2,
                 const float* __restrict__ rrow,
                 unsigned char* __restrict__ out, int M) {
    constexpr int BKT = 64, K = CDIM, N = DFFN, NT = K / BKT;
    __shared__ short As[2][128 * 64];
    __shared__ short Bs[2][64 * 64];
    __shared__ short Bs2[2][64 * 64];

    const int tid = threadIdx.x;
    const int bid = blockIdx.x;
    const int m0 = (bid >> 4) * 128;     // n-fastest: 16 consecutive blocks share A
    const int n0 = (bid & 15) * 64;
    const int wave = tid >> 6;
    const int lane = tid & 63;
    const int wm = (wave >> 1) * 64;
    const int wn = (wave & 1) * 32;
    const int fr = lane & 15;
    const int fq = lane >> 4;

    f32x4 acc[4][2] = {};
    f32x4 acc2[4][2] = {};

    // staging lane geometry: each 1024B chunk = 8 rows x 128B; lane L writes
    // LDS slot L*16 -> sources row chunkbase+(L>>3), col-chunk (L&7)^(L>>3).
    const int lrow = lane >> 3;           // 0..7
    const int lcol = (lane & 7) ^ lrow;   // pre-swizzled source col-chunk
    const char* Ab  = (const char*)A;
    const char* B1b = (const char*)B1;
    const char* B2b = (const char*)B2;

    auto stage = [&](int b, int k0) {
#pragma unroll
        for (int q = 0; q < 4; ++q) {          // A tile: 16 chunks, 4/wave
            const int c = wave * 4 + q;
            int gm = m0 + c * 8 + lrow;
            gm = (gm < M) ? gm : (M - 1);      // tail clamp (dead rows skipped in epilogue)
            gload16(Ab + ((size_t)gm * K + k0) * 2 + lcol * 16, (char*)As[b] + c * 1024);
        }
#pragma unroll
        for (int q = 0; q < 2; ++q) {          // B tiles: 8 chunks each, 2/wave
            const int c = wave * 2 + q;
            const size_t rn = (size_t)(n0 + c * 8 + lrow) * K + k0;
            gload16(B1b + rn * 2 + lcol * 16, (char*)Bs[b] + c * 1024);
            gload16(B2b + rn * 2 + lcol * 16, (char*)Bs2[b] + c * 1024);
        }
    };

    stage(0, 0);

    const int swz = (fr & 7) << 4;             // read-side byte XOR
#pragma unroll
    for (int t = 0; t < NT; ++t) {
        const int cur = t & 1;
        // barrier's implicit s_waitcnt vmcnt(0) drains buf[cur]'s loads
        // (issued last iteration, overlapped with last iteration's MFMAs)
        // and orders all waves past their previous compute (WAR for nxt).
        __syncthreads();
        if (t + 1 < NT) stage(cur ^ 1, (t + 1) * BKT);

#pragma unroll
        for (int kk = 0; kk < BKT; kk += 32) {
            const int co = ((kk * 2 + fq * 16) ^ swz) >> 1;   // short offset in row
            bf16x8 af[4], bfr[2], bg[2];
#pragma unroll
            for (int i = 0; i < 4; ++i)
                af[i] = *(const bf16x8*)&As[cur][(wm + i * 16 + fr) * 64 + co];
#pragma unroll
            for (int j = 0; j < 2; ++j) {
                bfr[j] = *(const bf16x8*)&Bs[cur][(wn + j * 16 + fr) * 64 + co];
                bg[j] = *(const bf16x8*)&Bs2[cur][(wn + j * 16 + fr) * 64 + co];
            }
#pragma unroll
            for (int i = 0; i < 4; ++i)
#pragma unroll
                for (int j = 0; j < 2; ++j) {
                    acc[i][j] = __builtin_amdgcn_mfma_f32_16x16x32_bf16(af[i], bfr[j], acc[i][j], 0, 0, 0);
                    acc2[i][j] = __builtin_amdgcn_mfma_f32_16x16x32_bf16(af[i], bg[j], acc2[i][j], 0, 0, 0);
                }
        }
    }

#pragma unroll
    for (int i = 0; i < 4; ++i) {
#pragma unroll
        for (int r = 0; r < 4; ++r) {
            const int m = m0 + wm + i * 16 + fq * 4 + r;
            if (m >= M) continue;
            const float rm = rrow[m];
#pragma unroll
            for (int j = 0; j < 2; ++j) {
                const int n = n0 + wn + j * 16 + fr;
                const float v1 = acc[i][j][r] * rm + bias1[n];
                const float v2 = acc2[i][j][r] * rm + bias2[n];
                const float sig = 1.0f / (1.0f + __expf(-v1));
                out[(size_t)m * N + n] = fp8_enc(v1 * sig * v2);
            }
        }
    }
}

// ---------------------------------------------------------------------------
// MSDeformAttn sampling (v4): 4 tokens/block, fp8 value, bf16 proj.
// ---------------------------------------------------------------------------
__global__ __launch_bounds__(256)
void sample_kernel(const unsigned char* __restrict__ value,
                   const ushort* __restrict__ proj,
                   const float* __restrict__ ref,
                   __hip_bfloat16* __restrict__ out) {
    __shared__ float wsm[4][NHD][16];
    __shared__ int2  sTap[4][64][9];

    const int tok0 = blockIdx.x * 4;
    const int t = threadIdx.x;

    if (t < 32) {
        const int tl = t >> 3, h = t & 7;
        const int row = tok0 + tl;
        if (row < MTOK) {
            const ushort* lg = &proj[(size_t)row * 384 + 256 + h * 16];
            float v[16];
            float mx = -3.4e38f;
#pragma unroll
            for (int i = 0; i < 16; ++i) {
                v[i] = __uint_as_float((unsigned)lg[i] << 16);
                mx = fmaxf(mx, v[i]);
            }
            float s = 0.f;
#pragma unroll
            for (int i = 0; i < 16; ++i) { v[i] = __expf(v[i] - mx); s += v[i]; }
            const float inv = 1.0f / s;
#pragma unroll
            for (int i = 0; i < 16; ++i) wsm[tl][h][i] = v[i] * inv;
        }
    }
    __syncthreads();

#pragma unroll
    for (int e = t; e < 512; e += 256) {
        const int tl = e >> 7, hp = e & 127;
        const int row = tok0 + tl;
        if (row < MTOK) {
            const int h = hp >> 4, pt = hp & 15, lv = pt >> 2;
            const int Hs[4] = {100, 50, 25, 13};
            const int Ws[4] = {134, 67, 34, 17};
            const int stt[4] = {0, 13400, 16750, 17600};
            const int H = Hs[lv], W = Ws[lv];
            const float rx = ref[((size_t)row * 4 + lv) * 2 + 0];
            const float ry = ref[((size_t)row * 4 + lv) * 2 + 1];
            const float ox = __uint_as_float((unsigned)proj[(size_t)row * 384 + h * 32 + pt * 2 + 0] << 16);
            const float oy = __uint_as_float((unsigned)proj[(size_t)row * 384 + h * 32 + pt * 2 + 1] << 16);
            const float xf = rx * (float)W + ox - 0.5f;
            const float yf = ry * (float)H + oy - 0.5f;
            const float x0f = floorf(xf), y0f = floorf(yf);
            const float fx = xf - x0f, fy = yf - y0f;
            const int x0 = (int)x0f, y0 = (int)y0f;
            const float aw = wsm[tl][h][pt];
            const int b = (row >= LQ) ? 1 : 0;
            const int base = (b * NHD + h) * LQ + stt[lv];
#pragma unroll
            for (int tap = 0; tap < 4; ++tap) {
                const int dy = tap >> 1, dx = tap & 1;
                const int xi = x0 + dx, yi = y0 + dy;
                const bool valid = (xi >= 0) & (xi < W) & (yi >= 0) & (yi < H);
                const float wgt = (dx ? fx : 1.f - fx) * (dy ? fy : 1.f - fy) * aw;
                sTap[tl][pt * 4 + tap][h] = valid
                    ? make_int2((base + yi * W + xi) * DHEAD, __float_as_int(wgt))
                    : make_int2(0, 0);
            }
        }
    }
    __syncthreads();

    const int tl = t >> 6, lane = t & 63;
    const int row = tok0 + tl;
    if (row >= MTOK) return;
    const int h = lane >> 3, c0 = (lane & 7) * 4;
    const unsigned char* vb = value + c0;
    float a0 = 0.f, a1 = 0.f, a2 = 0.f, a3 = 0.f;
#pragma unroll 8
    for (int i = 0; i < 64; ++i) {
        const int2 tp = sTap[tl][i][h];
        const float w = __int_as_float(tp.y);
        const unsigned d = *(const unsigned*)(vb + (size_t)tp.x);
        const f32x2 lo = fp8_dec2<false>(d);
        const f32x2 hi = fp8_dec2<true>(d);
        a0 = fmaf(w, lo[0], a0);
        a1 = fmaf(w, lo[1], a1);
        a2 = fmaf(w, hi[0], a2);
        a3 = fmaf(w, hi[1], a3);
    }
    ushort4 o;
    o.x = bfpack(a0); o.y = bfpack(a1); o.z = bfpack(a2); o.w = bfpack(a3);
    *(ushort4*)&out[(size_t)row * 256 + h * 32 + c0] = o;
}

// ---------------------------------------------------------------------------
// Workspace (bytes). MCb = 18.25 MB. Peak 7MCb + 2MB = 129.7 MB.
//   [0, MCb)              normed -> sampled
//   [MCb, 2MCb)           q -> x_bf
//   [2MCb, +9.1MB)        value fp8 -> (dead) r_f32 (142 KB)
//   [3MCb, +27.4MB)       proj bf16 -> (dead) h fp8 (36.5 MB) after sampling
//   [7MCb, +2MB)          bf16 weights
// ---------------------------------------------------------------------------
extern "C" void kernel_launch(void* const* d_in, const int* in_sizes, int n_in,
                              void* d_out, int out_size, void* d_ws, size_t ws_size,
                              hipStream_t stream) {
    const float* query      = (const float*)d_in[0];
    const float* query_pos  = (const float*)d_in[1];
    const float* ref        = (const float*)d_in[2];
    const float* norm_attn_w = (const float*)d_in[5];
    const float* Wv   = (const float*)d_in[6];
    const float* bv   = (const float*)d_in[7];
    const float* Woff = (const float*)d_in[8];
    const float* boff = (const float*)d_in[9];
    const float* Waw  = (const float*)d_in[10];
    const float* baw  = (const float*)d_in[11];
    const float* Wo   = (const float*)d_in[12];
    const float* bo   = (const float*)d_in[13];
    const float* ls_attn = (const float*)d_in[14];
    const float* norm_ffn_w = (const float*)d_in[15];
    const float* W1 = (const float*)d_in[16];
    const float* b1 = (const float*)d_in[17];
    const float* W2 = (const float*)d_in[18];
    const float* b2 = (const float*)d_in[19];
    const float* W3 = (const float*)d_in[20];
    const float* b3 = (const float*)d_in[21];
    const float* ls_ffn = (const float*)d_in[22];
    float* out = (float*)d_out;

    char* ws = (char*)d_ws;
    const size_t MCb = (size_t)MTOK * CDIM * 2;   // 18,248,704

    __hip_bfloat16* normed_bf  = (__hip_bfloat16*)(ws);
    __hip_bfloat16* q_bf       = (__hip_bfloat16*)(ws + MCb);
    unsigned char*  value_u8   = (unsigned char*)(ws + 2 * MCb);
    __hip_bfloat16* proj_bf    = (__hip_bfloat16*)(ws + 3 * MCb);
    __hip_bfloat16* sampled_bf = (__hip_bfloat16*)(ws);             // after normed/q dead
    __hip_bfloat16* x_bf       = (__hip_bfloat16*)(ws + MCb);       // after q dead
    float*          r_f        = (float*)(ws + 2 * MCb);            // after value dead
    unsigned char*  h_u8       = (unsigned char*)(ws + 3 * MCb);    // after proj dead
    __hip_bfloat16* wbf        = (__hip_bfloat16*)(ws + 7 * MCb);

    __hip_bfloat16* Wv_bf    = wbf;
    __hip_bfloat16* Wproj_bf = wbf + 65536;    // Woff (256 rows) ++ Waw (128 rows)
    __hip_bfloat16* Wo_bf    = wbf + 163840;
    __hip_bfloat16* W1_bf    = wbf + 229376;   // norm_ffn_w folded
    __hip_bfloat16* W2_bf    = wbf + 491520;   // norm_ffn_w folded
    __hip_bfloat16* W3_bf    = wbf + 753664;

    // 0. all weight casts in one dispatch (W1/W2 get norm_ffn_w column-folded)
    CastJobs cj;
    cj.src[0] = Wv;   cj.dst[0] = Wv_bf;            cj.colw[0] = nullptr; cj.n[0] = 65536;
    cj.src[1] = Woff; cj.dst[1] = Wproj_bf;         cj.colw[1] = nullptr; cj.n[1] = 65536;
    cj.src[2] = Waw;  cj.dst[2] = Wproj_bf + 65536; cj.colw[2] = nullptr; cj.n[2] = 32768;
    cj.src[3] = Wo;   cj.dst[3] = Wo_bf;            cj.colw[3] = nullptr; cj.n[3] = 65536;
    cj.src[4] = W1;   cj.dst[4] = W1_bf;            cj.colw[4] = norm_ffn_w; cj.n[4] = 262144;
    cj.src[5] = W2;   cj.dst[5] = W2_bf;            cj.colw[5] = norm_ffn_w; cj.n[5] = 262144;
    cj.src[6] = W3;   cj.dst[6] = W3_bf;            cj.colw[6] = nullptr; cj.n[6] = 262144;
    cast_all<<<dim3(1024, 7), 256, 0, stream>>>(cj);

    const int gx = (MTOK + GBM - 1) / GBM;   // 279
    const int gr = (MTOK + 3) / 4;           // 8911

    // 1. normed_bf, q_bf = normed + pos
    rmsnorm_kernel<true><<<gr, 256, 0, stream>>>(query, query_pos, norm_attn_w, normed_bf, q_bf);
    // 2. value = normed @ Wv^T + bv -> fp8 (b,h,q,c)
    mfma_gemm<1, 64, unsigned char><<<gx * 2, 256, 0, stream>>>(
        normed_bf, Wv_bf, bv, nullptr, nullptr, nullptr, nullptr, value_u8, MTOK, CDIM, CDIM, 2);
    // 3. proj = q @ [Woff;Waw]^T + [boff;baw] -> bf16 (M,384)
    mfma_gemm<4, 64, __hip_bfloat16><<<gx * 3, 256, 0, stream>>>(
        q_bf, Wproj_bf, boff, baw, nullptr, nullptr, nullptr, proj_bf, MTOK, 384, CDIM, 3);
    // 4. deformable sampling -> sampled_bf
    sample_kernel<<<gr, 256, 0, stream>>>(value_u8, (const ushort*)proj_bf, ref, sampled_bf);
    // 5. x = query + ls_attn * (sampled @ Wo^T + bo) -> bf16
    mfma_gemm<2, 64, __hip_bfloat16><<<gx * 2, 256, 0, stream>>>(
        sampled_bf, Wo_bf, bo, nullptr, query, nullptr, ls_attn, x_bf, MTOK, CDIM, CDIM, 2);
    // 6. r[m] = rsqrt(mean(x^2)+eps)
    rowrms_kernel<<<gr, 256, 0, stream>>>(x_bf, r_f);
    // 7. h = silu(r*(x@W1'^T)+b1) * (r*(x@W2'^T)+b2) -> fp8
    mfma_swiglu<<<gx * 16, 256, 0, stream>>>(
        x_bf, W1_bf, b1, W2_bf, b2, r_f, h_u8, MTOK);
    // 8. out = x + ls_ffn * (h @ W3^T + b3) -> f32 (A is fp8)
    mfma_gemm<5, 64, float, true><<<gx * 2, 256, 0, stream>>>(
        h_u8, W3_bf, b3, nullptr, nullptr, x_bf, ls_ffn, out, MTOK, CDIM, DFFN, 2);
}

// Round 7
// 387.346 us; speedup vs baseline: 1.0145x; 1.0145x over previous
//
#include <hip/hip_runtime.h>
#include <hip/hip_bf16.h>
#include <cstddef>

// Problem constants (static shapes from the reference)
#define LQ   17821
#define BS   2
#define MTOK (BS * LQ)       // 35642 token rows
#define CDIM 256
#define NHD  8
#define DHEAD 32
#define DFFN 1024

typedef short bf16x4 __attribute__((ext_vector_type(4)));
typedef short bf16x8 __attribute__((ext_vector_type(8)));
typedef float f32x4  __attribute__((ext_vector_type(4)));
typedef float f32x2  __attribute__((ext_vector_type(2)));

typedef const __attribute__((address_space(1))) unsigned char gcu8;
typedef __attribute__((address_space(3))) unsigned char lu8;

// async global->LDS, 16B per lane, dest = wave-uniform base + lane*16 (linear)
__device__ __forceinline__ void gload16(const void* g, void* l) {
    __builtin_amdgcn_global_load_lds((gcu8*)g, (lu8*)l, 16, 0, 0);
}

// ---------------------------------------------------------------------------
// fp8 e4m3 (OCP) encode/decode helpers — HW path with SW fallback
// ---------------------------------------------------------------------------
__device__ __forceinline__ unsigned char fp8_enc(float f) {
#if __has_builtin(__builtin_amdgcn_cvt_pk_fp8_f32)
    return (unsigned char)(__builtin_amdgcn_cvt_pk_fp8_f32(f, f, 0, false) & 0xff);
#else
    unsigned s = (__float_as_uint(f) >> 31) << 7;
    float af = fabsf(f);
    if (af < 0.0078125f) return (unsigned char)s;   // flush tiny/subnormal
    af = fminf(af, 448.f);
    unsigned b = __float_as_uint(af);
    int e = (int)(b >> 23) - 127 + 7;
    unsigned m = (b >> 20) & 7;
    if (b & 0x80000) { m++; if (m == 8) { m = 0; e++; } }
    if (e < 1) return (unsigned char)s;
    if (e > 15) { e = 15; m = 6; }
    return (unsigned char)(s | ((unsigned)e << 3) | m);
#endif
}

__device__ __forceinline__ float fp8_dec_byte(unsigned x) {
    unsigned s = (x >> 7) & 1, e = (x >> 3) & 15, m = x & 7;
    float v = e ? __uint_as_float(((e + 120u) << 23) | (m << 20))
                : (float)m * 0.001953125f;
    return s ? -v : v;
}

// Decode 2 fp8 bytes (low pair HI=false, high pair HI=true) of a dword.
template <bool HI>
__device__ __forceinline__ f32x2 fp8_dec2(unsigned d) {
#if __has_builtin(__builtin_amdgcn_cvt_pk_f32_fp8)
    return __builtin_amdgcn_cvt_pk_f32_fp8(d, HI);
#else
    f32x2 r;
    r[0] = fp8_dec_byte((d >> (HI ? 16 : 0)) & 0xff);
    r[1] = fp8_dec_byte((d >> (HI ? 24 : 8)) & 0xff);
    return r;
#endif
}

__device__ __forceinline__ ushort bfpack(float f) {
    __hip_bfloat16 h = (__hip_bfloat16)f;
    return *(ushort*)&h;
}

// Stage 8 fp8 bytes (uint2) -> 8 bf16 in LDS
__device__ __forceinline__ void stage_a8(short* p, uint2 d) {
    const f32x2 p0 = fp8_dec2<false>(d.x), p1 = fp8_dec2<true>(d.x);
    const f32x2 p2 = fp8_dec2<false>(d.y), p3 = fp8_dec2<true>(d.y);
    bf16x4 lo, hi;
    lo[0] = (short)bfpack(p0[0]); lo[1] = (short)bfpack(p0[1]);
    lo[2] = (short)bfpack(p1[0]); lo[3] = (short)bfpack(p1[1]);
    hi[0] = (short)bfpack(p2[0]); hi[1] = (short)bfpack(p2[1]);
    hi[2] = (short)bfpack(p3[0]); hi[3] = (short)bfpack(p3[1]);
    ((bf16x4*)p)[0] = lo;
    ((bf16x4*)p)[1] = hi;
}

// ---------------------------------------------------------------------------
// Batched fp32 -> bf16 weight cast; optional per-column scale (norm folding)
// ---------------------------------------------------------------------------
struct CastJobs {
    const float* src[7];
    __hip_bfloat16* dst[7];
    const float* colw[7];   // if non-null: dst = src * colw[i & 255]
    int n[7];
};

__global__ __launch_bounds__(256)
void cast_all(CastJobs j) {
    const int seg = blockIdx.y;
    const int i = blockIdx.x * 256 + threadIdx.x;
    if (i < j.n[seg]) {
        float v = j.src[seg][i];
        if (j.colw[seg]) v *= j.colw[seg][i & 255];
        j.dst[seg][i] = (__hip_bfloat16)v;
    }
}

// ---------------------------------------------------------------------------
// RMSNorm, wave-per-token (64 lanes x float4 = 256 ch), 4 tokens/block.
// ---------------------------------------------------------------------------
template <bool ADD_POS>
__global__ __launch_bounds__(256)
void rmsnorm_kernel(const float* __restrict__ x, const float* __restrict__ pos,
                    const float* __restrict__ w,
                    __hip_bfloat16* __restrict__ outN, __hip_bfloat16* __restrict__ outQ) {
    const int tok = blockIdx.x * 4 + (threadIdx.x >> 6);
    if (tok >= MTOK) return;
    const int lane = threadIdx.x & 63;
    const size_t base = (size_t)tok * CDIM + lane * 4;
    const float4 v = *(const float4*)&x[base];
    float ss = v.x * v.x + v.y * v.y + v.z * v.z + v.w * v.w;
#pragma unroll
    for (int m = 1; m < 64; m <<= 1) ss += __shfl_xor(ss, m, 64);
    const float r = rsqrtf(ss * (1.0f / CDIM) + 1e-6f);
    const float4 wv = *(const float4*)&w[lane * 4];
    const float n0 = v.x * r * wv.x, n1 = v.y * r * wv.y;
    const float n2 = v.z * r * wv.z, n3 = v.w * r * wv.w;
    ushort4 o;
    o.x = bfpack(n0); o.y = bfpack(n1); o.z = bfpack(n2); o.w = bfpack(n3);
    *(ushort4*)&outN[base] = o;
    if (ADD_POS) {
        const float4 p = *(const float4*)&pos[base];
        ushort4 q;
        q.x = bfpack(n0 + p.x); q.y = bfpack(n1 + p.y);
        q.z = bfpack(n2 + p.z); q.w = bfpack(n3 + p.w);
        *(ushort4*)&outQ[base] = q;
    }
}

// ---------------------------------------------------------------------------
// Row RMS scale only: r[m] = rsqrt(mean(x^2)+eps), x bf16. 4 tokens/block.
// ---------------------------------------------------------------------------
__global__ __launch_bounds__(256)
void rowrms_kernel(const __hip_bfloat16* __restrict__ x, float* __restrict__ r) {
    const int tok = blockIdx.x * 4 + (threadIdx.x >> 6);
    if (tok >= MTOK) return;
    const int lane = threadIdx.x & 63;
    const ushort4 u = *(const ushort4*)&x[(size_t)tok * CDIM + lane * 4];
    const float v0 = __uint_as_float((unsigned)u.x << 16);
    const float v1 = __uint_as_float((unsigned)u.y << 16);
    const float v2 = __uint_as_float((unsigned)u.z << 16);
    const float v3 = __uint_as_float((unsigned)u.w << 16);
    float ss = v0 * v0 + v1 * v1 + v2 * v2 + v3 * v3;
#pragma unroll
    for (int m = 1; m < 64; m <<= 1) ss += __shfl_xor(ss, m, 64);
    if (lane == 0) r[tok] = rsqrtf(ss * (1.0f / CDIM) + 1e-6f);
}

// ---------------------------------------------------------------------------
// bf16 MFMA GEMM: C[M,N] = A[M,K] @ W[N,K]^T (+ epilogues), fp32 accumulate.
// 128x128 block tile, templated BK, 4 waves (2x2), wave = 4x4 of 16x16x32.
// Flat grid, n-fastest swizzle: m0 = bid/nsw, n0 = bid%nsw (L2 A-reuse).
// A8: A operand stored fp8 e4m3, decoded to bf16 during LDS staging.
// MODE 0: out = acc + bias1
// MODE 1: value layout write (b, h, q, c), fp8 e4m3
// MODE 2: out = resid_f32 + ls * (acc + bias1)
// MODE 4: out = acc + concat(bias1[0:256], bias2[0:128])[n]   (proj N=384)
// MODE 5: out = resid_bf16 + ls * (acc + bias1), f32 out
// ---------------------------------------------------------------------------
#define GBM 128
#define GBN 128

template <int MODE, int BKT, typename OUTT, bool A8 = false>
__global__ __launch_bounds__(256, 2)
void mfma_gemm(const void* __restrict__ Av,
               const __hip_bfloat16* __restrict__ B1, const float* __restrict__ bias1,
               const float* __restrict__ bias2,
               const float* __restrict__ resid, const __hip_bfloat16* __restrict__ residb,
               const float* __restrict__ ls,
               OUTT* __restrict__ out, int M, int N, int K, int nsw) {
    constexpr int LDKT = BKT + 8;        // +16B pad: 2-way bank alias (free)
    constexpr int CH = BKT / 16;         // staging chunks per thread per matrix
    constexpr int CPR = BKT / 8;         // 8-elem chunks per row

    __shared__ short As[GBM * LDKT];
    __shared__ short Bs[GBN * LDKT];

    const __hip_bfloat16* A = (const __hip_bfloat16*)Av;
    const unsigned char* A8p = (const unsigned char*)Av;

    const int tid = threadIdx.x;
    const int bid = blockIdx.x;
    const int m0 = (bid / nsw) * GBM;
    const int n0 = (bid % nsw) * GBN;
    const int wave = tid >> 6;
    const int lane = tid & 63;
    const int wm = (wave >> 1) * 64;
    const int wn = (wave & 1) * 64;
    const int fr = lane & 15;   // col of C
    const int fq = lane >> 4;   // quad: k = fq*8+j ; C row = fq*4+r

    f32x4 acc[4][4] = {};

    int srow[CH], skc[CH];
#pragma unroll
    for (int cc = 0; cc < CH; ++cc) {
        const int g = tid + cc * 256;
        srow[cc] = g / CPR;
        skc[cc] = (g % CPR) * 8;
    }
    const uint4 zero4 = make_uint4(0, 0, 0, 0);
    const uint2 zero2 = make_uint2(0, 0);

    uint4 ra[CH], rb[CH];
    uint2 ra8[A8 ? CH : 1];
#pragma unroll
    for (int cc = 0; cc < CH; ++cc) {
        const int gm = m0 + srow[cc];
        if constexpr (A8)
            ra8[cc] = (gm < M) ? *(const uint2*)&A8p[(size_t)gm * K + skc[cc]] : zero2;
        else
            ra[cc] = (gm < M) ? *(const uint4*)&A[(size_t)gm * K + skc[cc]] : zero4;
        rb[cc] = *(const uint4*)&B1[(size_t)(n0 + srow[cc]) * K + skc[cc]];
    }

    for (int k0 = 0; k0 < K; k0 += BKT) {
        __syncthreads();
#pragma unroll
        for (int cc = 0; cc < CH; ++cc) {
            short* pa = &As[srow[cc] * LDKT + skc[cc]];
            short* pb = &Bs[srow[cc] * LDKT + skc[cc]];
            if constexpr (A8) {
                stage_a8(pa, ra8[cc]);
            } else {
                union { uint4 u; bf16x4 h[2]; } cv;
                cv.u = ra[cc]; ((bf16x4*)pa)[0] = cv.h[0]; ((bf16x4*)pa)[1] = cv.h[1];
            }
            union { uint4 u; bf16x4 h[2]; } cv;
            cv.u = rb[cc]; ((bf16x4*)pb)[0] = cv.h[0]; ((bf16x4*)pb)[1] = cv.h[1];
        }
        __syncthreads();

        if (k0 + BKT < K) {
            const int kn = k0 + BKT;
#pragma unroll
            for (int cc = 0; cc < CH; ++cc) {
                const int gm = m0 + srow[cc];
                if constexpr (A8)
                    ra8[cc] = (gm < M) ? *(const uint2*)&A8p[(size_t)gm * K + kn + skc[cc]] : zero2;
                else
                    ra[cc] = (gm < M) ? *(const uint4*)&A[(size_t)gm * K + kn + skc[cc]] : zero4;
                rb[cc] = *(const uint4*)&B1[(size_t)(n0 + srow[cc]) * K + kn + skc[cc]];
            }
        }

#pragma unroll
        for (int kk = 0; kk < BKT; kk += 32) {
            const int kq = kk + fq * 8;
            bf16x8 af[4], bfr[4];
#pragma unroll
            for (int i = 0; i < 4; ++i)
                af[i] = *(const bf16x8*)&As[(wm + i * 16 + fr) * LDKT + kq];
#pragma unroll
            for (int j = 0; j < 4; ++j)
                bfr[j] = *(const bf16x8*)&Bs[(wn + j * 16 + fr) * LDKT + kq];
#pragma unroll
            for (int i = 0; i < 4; ++i)
#pragma unroll
                for (int j = 0; j < 4; ++j)
                    acc[i][j] = __builtin_amdgcn_mfma_f32_16x16x32_bf16(af[i], bfr[j], acc[i][j], 0, 0, 0);
        }
    }

#pragma unroll
    for (int i = 0; i < 4; ++i) {
#pragma unroll
        for (int r = 0; r < 4; ++r) {
            const int m = m0 + wm + i * 16 + fq * 4 + r;
            if (m >= M) continue;
#pragma unroll
            for (int j = 0; j < 4; ++j) {
                const int n = n0 + wn + j * 16 + fr;
                float v;
                if constexpr (MODE == 4)
                    v = acc[i][j][r] + ((n < 256) ? bias1[n] : bias2[n - 256]);
                else
                    v = acc[i][j][r] + bias1[n];
                if constexpr (MODE == 0 || MODE == 4) {
                    out[(size_t)m * N + n] = (OUTT)v;
                } else if constexpr (MODE == 1) {
                    const int b = (m >= LQ) ? 1 : 0;
                    const int qi = m - b * LQ;
                    const int h = n >> 5;
                    const int c = n & 31;
                    ((unsigned char*)out)[((size_t)(b * NHD + h) * LQ + qi) * DHEAD + c] = fp8_enc(v);
                } else if constexpr (MODE == 2) {
                    out[(size_t)m * N + n] =
                        (OUTT)(resid[(size_t)m * N + n] + ls[n] * v);
                } else {  // MODE 5: bf16 residual, f32 out
                    const float rx = __uint_as_float(
                        (unsigned)(*(const ushort*)&residb[(size_t)m * N + n]) << 16);
                    out[(size_t)m * N + n] = (OUTT)(rx + ls[n] * v);
                }
            }
        }
    }
}

// ---------------------------------------------------------------------------
// SwiGLU dual GEMM: h = silu(r[m]*(x@W1'^T)+b1) * (r[m]*(x@W2'^T)+b2)
// 128x64 block tile, BK=32, DOUBLE-BUFFERED global_load_lds staging with
// TOTAL LDS = 32KB (2 x 16KB): combines round-6's overlap (stage t+1 issued
// before compute t) with round-5's occupancy (3-4 blocks/CU).
// Swizzle (BK=32 geometry): row = 64B, chunk = 1024B = 16 rows. Slot
// (row, cb) holds data (row, cb ^ (((row>>1)&3)<<4)); write lane L sources
// col-chunk (L&3)^((L>>3)&3) of row L>>2; read XORs ((fr>>1)&3)<<4.
// 16 read lanes -> 8 bank-slots x 2 = 2-way (free).
// ---------------------------------------------------------------------------
__global__ __launch_bounds__(256, 3)
void mfma_swiglu(const __hip_bfloat16* __restrict__ A,
                 const __hip_bfloat16* __restrict__ B1, const float* __restrict__ bias1,
                 const __hip_bfloat16* __restrict__ B2, const float* __restrict__ bias2,
                 const float* __restrict__ rrow,
                 unsigned char* __restrict__ out, int M) {
    constexpr int BKT = 32, K = CDIM, N = DFFN, NT = K / BKT;   // NT = 8
    __shared__ short As[2][128 * 32];
    __shared__ short Bs[2][64 * 32];
    __shared__ short Bs2[2][64 * 32];

    const int tid = threadIdx.x;
    const int bid = blockIdx.x;
    const int m0 = (bid >> 4) * 128;     // n-fastest: 16 consecutive blocks share A
    const int n0 = (bid & 15) * 64;
    const int wave = tid >> 6;
    const int lane = tid & 63;
    const int wm = (wave >> 1) * 64;
    const int wn = (wave & 1) * 32;
    const int fr = lane & 15;
    const int fq = lane >> 4;

    f32x4 acc[4][2] = {};
    f32x4 acc2[4][2] = {};

    // staging lane geometry (1024B chunk = 16 rows x 64B):
    // lane L writes LDS slot L*16 -> sources row chunk0+(L>>2),
    // col-chunk (L&3)^((L>>3)&3)  [= (L&3) ^ ((lrow>>1)&3)]
    const int lrow = lane >> 2;                 // 0..15
    const int lcol = (lane & 3) ^ ((lane >> 3) & 3);
    const char* Ab  = (const char*)A;
    const char* B1b = (const char*)B1;
    const char* B2b = (const char*)B2;

    auto stage = [&](int b, int k0) {
#pragma unroll
        for (int q = 0; q < 2; ++q) {           // A tile: 8 chunks, 2/wave
            const int c = wave * 2 + q;
            int gm = m0 + c * 16 + lrow;
            gm = (gm < M) ? gm : (M - 1);       // tail clamp (dead rows skipped in epilogue)
            gload16(Ab + ((size_t)gm * K + k0) * 2 + lcol * 16, (char*)As[b] + c * 1024);
        }
        {                                        // B tiles: 4 chunks each, 1/wave
            const size_t rn = (size_t)(n0 + wave * 16 + lrow) * K + k0;
            gload16(B1b + rn * 2 + lcol * 16, (char*)Bs[b] + wave * 1024);
            gload16(B2b + rn * 2 + lcol * 16, (char*)Bs2[b] + wave * 1024);
        }
    };

    stage(0, 0);

    const int swz = ((fr >> 1) & 3) << 3;        // read-side XOR, in shorts
    const int co = (fq * 8) ^ swz;               // col short offset within row
#pragma unroll
    for (int t = 0; t < NT; ++t) {
        const int cur = t & 1;
        // barrier's implicit s_waitcnt vmcnt(0) drains buf[cur]'s loads
        // (issued last iteration, overlapped with last iteration's MFMAs)
        // and orders all waves past their previous compute (WAR for nxt).
        __syncthreads();
        if (t + 1 < NT) stage(cur ^ 1, (t + 1) * BKT);

        bf16x8 af[4], bfr[2], bg[2];
#pragma unroll
        for (int i = 0; i < 4; ++i)
            af[i] = *(const bf16x8*)&As[cur][(wm + i * 16 + fr) * 32 + co];
#pragma unroll
        for (int j = 0; j < 2; ++j) {
            bfr[j] = *(const bf16x8*)&Bs[cur][(wn + j * 16 + fr) * 32 + co];
            bg[j] = *(const bf16x8*)&Bs2[cur][(wn + j * 16 + fr) * 32 + co];
        }
#pragma unroll
        for (int i = 0; i < 4; ++i)
#pragma unroll
            for (int j = 0; j < 2; ++j) {
                acc[i][j] = __builtin_amdgcn_mfma_f32_16x16x32_bf16(af[i], bfr[j], acc[i][j], 0, 0, 0);
                acc2[i][j] = __builtin_amdgcn_mfma_f32_16x16x32_bf16(af[i], bg[j], acc2[i][j], 0, 0, 0);
            }
    }

#pragma unroll
    for (int i = 0; i < 4; ++i) {
#pragma unroll
        for (int r = 0; r < 4; ++r) {
            const int m = m0 + wm + i * 16 + fq * 4 + r;
            if (m >= M) continue;
            const float rm = rrow[m];
#pragma unroll
            for (int j = 0; j < 2; ++j) {
                const int n = n0 + wn + j * 16 + fr;
                const float v1 = acc[i][j][r] * rm + bias1[n];
                const float v2 = acc2[i][j][r] * rm + bias2[n];
                const float sig = 1.0f / (1.0f + __expf(-v1));
                out[(size_t)m * N + n] = fp8_enc(v1 * sig * v2);
            }
        }
    }
}

// ---------------------------------------------------------------------------
// MSDeformAttn sampling (v4): 4 tokens/block, fp8 value, bf16 proj.
// ---------------------------------------------------------------------------
__global__ __launch_bounds__(256)
void sample_kernel(const unsigned char* __restrict__ value,
                   const ushort* __restrict__ proj,
                   const float* __restrict__ ref,
                   __hip_bfloat16* __restrict__ out) {
    __shared__ float wsm[4][NHD][16];
    __shared__ int2  sTap[4][64][9];

    const int tok0 = blockIdx.x * 4;
    const int t = threadIdx.x;

    if (t < 32) {
        const int tl = t >> 3, h = t & 7;
        const int row = tok0 + tl;
        if (row < MTOK) {
            const ushort* lg = &proj[(size_t)row * 384 + 256 + h * 16];
            float v[16];
            float mx = -3.4e38f;
#pragma unroll
            for (int i = 0; i < 16; ++i) {
                v[i] = __uint_as_float((unsigned)lg[i] << 16);
                mx = fmaxf(mx, v[i]);
            }
            float s = 0.f;
#pragma unroll
            for (int i = 0; i < 16; ++i) { v[i] = __expf(v[i] - mx); s += v[i]; }
            const float inv = 1.0f / s;
#pragma unroll
            for (int i = 0; i < 16; ++i) wsm[tl][h][i] = v[i] * inv;
        }
    }
    __syncthreads();

#pragma unroll
    for (int e = t; e < 512; e += 256) {
        const int tl = e >> 7, hp = e & 127;
        const int row = tok0 + tl;
        if (row < MTOK) {
            const int h = hp >> 4, pt = hp & 15, lv = pt >> 2;
            const int Hs[4] = {100, 50, 25, 13};
            const int Ws[4] = {134, 67, 34, 17};
            const int stt[4] = {0, 13400, 16750, 17600};
            const int H = Hs[lv], W = Ws[lv];
            const float rx = ref[((size_t)row * 4 + lv) * 2 + 0];
            const float ry = ref[((size_t)row * 4 + lv) * 2 + 1];
            const float ox = __uint_as_float((unsigned)proj[(size_t)row * 384 + h * 32 + pt * 2 + 0] << 16);
            const float oy = __uint_as_float((unsigned)proj[(size_t)row * 384 + h * 32 + pt * 2 + 1] << 16);
            const float xf = rx * (float)W + ox - 0.5f;
            const float yf = ry * (float)H + oy - 0.5f;
            const float x0f = floorf(xf), y0f = floorf(yf);
            const float fx = xf - x0f, fy = yf - y0f;
            const int x0 = (int)x0f, y0 = (int)y0f;
            const float aw = wsm[tl][h][pt];
            const int b = (row >= LQ) ? 1 : 0;
            const int base = (b * NHD + h) * LQ + stt[lv];
#pragma unroll
            for (int tap = 0; tap < 4; ++tap) {
                const int dy = tap >> 1, dx = tap & 1;
                const int xi = x0 + dx, yi = y0 + dy;
                const bool valid = (xi >= 0) & (xi < W) & (yi >= 0) & (yi < H);
                const float wgt = (dx ? fx : 1.f - fx) * (dy ? fy : 1.f - fy) * aw;
                sTap[tl][pt * 4 + tap][h] = valid
                    ? make_int2((base + yi * W + xi) * DHEAD, __float_as_int(wgt))
                    : make_int2(0, 0);
            }
        }
    }
    __syncthreads();

    const int tl = t >> 6, lane = t & 63;
    const int row = tok0 + tl;
    if (row >= MTOK) return;
    const int h = lane >> 3, c0 = (lane & 7) * 4;
    const unsigned char* vb = value + c0;
    float a0 = 0.f, a1 = 0.f, a2 = 0.f, a3 = 0.f;
#pragma unroll 8
    for (int i = 0; i < 64; ++i) {
        const int2 tp = sTap[tl][i][h];
        const float w = __int_as_float(tp.y);
        const unsigned d = *(const unsigned*)(vb + (size_t)tp.x);
        const f32x2 lo = fp8_dec2<false>(d);
        const f32x2 hi = fp8_dec2<true>(d);
        a0 = fmaf(w, lo[0], a0);
        a1 = fmaf(w, lo[1], a1);
        a2 = fmaf(w, hi[0], a2);
        a3 = fmaf(w, hi[1], a3);
    }
    ushort4 o;
    o.x = bfpack(a0); o.y = bfpack(a1); o.z = bfpack(a2); o.w = bfpack(a3);
    *(ushort4*)&out[(size_t)row * 256 + h * 32 + c0] = o;
}

// ---------------------------------------------------------------------------
// Workspace (bytes). MCb = 18.25 MB. Peak 7MCb + 2MB = 129.7 MB.
//   [0, MCb)              normed -> sampled
//   [MCb, 2MCb)           q -> x_bf
//   [2MCb, +9.1MB)        value fp8 -> (dead) r_f32 (142 KB)
//   [3MCb, +27.4MB)       proj bf16 -> (dead) h fp8 (36.5 MB) after sampling
//   [7MCb, +2MB)          bf16 weights
// ---------------------------------------------------------------------------
extern "C" void kernel_launch(void* const* d_in, const int* in_sizes, int n_in,
                              void* d_out, int out_size, void* d_ws, size_t ws_size,
                              hipStream_t stream) {
    const float* query      = (const float*)d_in[0];
    const float* query_pos  = (const float*)d_in[1];
    const float* ref        = (const float*)d_in[2];
    const float* norm_attn_w = (const float*)d_in[5];
    const float* Wv   = (const float*)d_in[6];
    const float* bv   = (const float*)d_in[7];
    const float* Woff = (const float*)d_in[8];
    const float* boff = (const float*)d_in[9];
    const float* Waw  = (const float*)d_in[10];
    const float* baw  = (const float*)d_in[11];
    const float* Wo   = (const float*)d_in[12];
    const float* bo   = (const float*)d_in[13];
    const float* ls_attn = (const float*)d_in[14];
    const float* norm_ffn_w = (const float*)d_in[15];
    const float* W1 = (const float*)d_in[16];
    const float* b1 = (const float*)d_in[17];
    const float* W2 = (const float*)d_in[18];
    const float* b2 = (const float*)d_in[19];
    const float* W3 = (const float*)d_in[20];
    const float* b3 = (const float*)d_in[21];
    const float* ls_ffn = (const float*)d_in[22];
    float* out = (float*)d_out;

    char* ws = (char*)d_ws;
    const size_t MCb = (size_t)MTOK * CDIM * 2;   // 18,248,704

    __hip_bfloat16* normed_bf  = (__hip_bfloat16*)(ws);
    __hip_bfloat16* q_bf       = (__hip_bfloat16*)(ws + MCb);
    unsigned char*  value_u8   = (unsigned char*)(ws + 2 * MCb);
    __hip_bfloat16* proj_bf    = (__hip_bfloat16*)(ws + 3 * MCb);
    __hip_bfloat16* sampled_bf = (__hip_bfloat16*)(ws);             // after normed/q dead
    __hip_bfloat16* x_bf       = (__hip_bfloat16*)(ws + MCb);       // after q dead
    float*          r_f        = (float*)(ws + 2 * MCb);            // after value dead
    unsigned char*  h_u8       = (unsigned char*)(ws + 3 * MCb);    // after proj dead
    __hip_bfloat16* wbf        = (__hip_bfloat16*)(ws + 7 * MCb);

    __hip_bfloat16* Wv_bf    = wbf;
    __hip_bfloat16* Wproj_bf = wbf + 65536;    // Woff (256 rows) ++ Waw (128 rows)
    __hip_bfloat16* Wo_bf    = wbf + 163840;
    __hip_bfloat16* W1_bf    = wbf + 229376;   // norm_ffn_w folded
    __hip_bfloat16* W2_bf    = wbf + 491520;   // norm_ffn_w folded
    __hip_bfloat16* W3_bf    = wbf + 753664;

    // 0. all weight casts in one dispatch (W1/W2 get norm_ffn_w column-folded)
    CastJobs cj;
    cj.src[0] = Wv;   cj.dst[0] = Wv_bf;            cj.colw[0] = nullptr; cj.n[0] = 65536;
    cj.src[1] = Woff; cj.dst[1] = Wproj_bf;         cj.colw[1] = nullptr; cj.n[1] = 65536;
    cj.src[2] = Waw;  cj.dst[2] = Wproj_bf + 65536; cj.colw[2] = nullptr; cj.n[2] = 32768;
    cj.src[3] = Wo;   cj.dst[3] = Wo_bf;            cj.colw[3] = nullptr; cj.n[3] = 65536;
    cj.src[4] = W1;   cj.dst[4] = W1_bf;            cj.colw[4] = norm_ffn_w; cj.n[4] = 262144;
    cj.src[5] = W2;   cj.dst[5] = W2_bf;            cj.colw[5] = norm_ffn_w; cj.n[5] = 262144;
    cj.src[6] = W3;   cj.dst[6] = W3_bf;            cj.colw[6] = nullptr; cj.n[6] = 262144;
    cast_all<<<dim3(1024, 7), 256, 0, stream>>>(cj);

    const int gx = (MTOK + GBM - 1) / GBM;   // 279
    const int gr = (MTOK + 3) / 4;           // 8911

    // 1. normed_bf, q_bf = normed + pos
    rmsnorm_kernel<true><<<gr, 256, 0, stream>>>(query, query_pos, norm_attn_w, normed_bf, q_bf);
    // 2. value = normed @ Wv^T + bv -> fp8 (b,h,q,c)
    mfma_gemm<1, 64, unsigned char><<<gx * 2, 256, 0, stream>>>(
        normed_bf, Wv_bf, bv, nullptr, nullptr, nullptr, nullptr, value_u8, MTOK, CDIM, CDIM, 2);
    // 3. proj = q @ [Woff;Waw]^T + [boff;baw] -> bf16 (M,384)
    mfma_gemm<4, 64, __hip_bfloat16><<<gx * 3, 256, 0, stream>>>(
        q_bf, Wproj_bf, boff, baw, nullptr, nullptr, nullptr, proj_bf, MTOK, 384, CDIM, 3);
    // 4. deformable sampling -> sampled_bf
    sample_kernel<<<gr, 256, 0, stream>>>(value_u8, (const ushort*)proj_bf, ref, sampled_bf);
    // 5. x = query + ls_attn * (sampled @ Wo^T + bo) -> bf16
    mfma_gemm<2, 64, __hip_bfloat16><<<gx * 2, 256, 0, stream>>>(
        sampled_bf, Wo_bf, bo, nullptr, query, nullptr, ls_attn, x_bf, MTOK, CDIM, CDIM, 2);
    // 6. r[m] = rsqrt(mean(x^2)+eps)
    rowrms_kernel<<<gr, 256, 0, stream>>>(x_bf, r_f);
    // 7. h = silu(r*(x@W1'^T)+b1) * (r*(x@W2'^T)+b2) -> fp8
    mfma_swiglu<<<gx * 16, 256, 0, stream>>>(
        x_bf, W1_bf, b1, W2_bf, b2, r_f, h_u8, MTOK);
    // 8. out = x + ls_ffn * (h @ W3^T + b3) -> f32 (A is fp8)
    mfma_gemm<5, 64, float, true><<<gx * 2, 256, 0, stream>>>(
        h_u8, W3_bf, b3, nullptr, nullptr, x_bf, ls_ffn, out, MTOK, CDIM, DFFN, 2);
}

// Round 8
// 374.349 us; speedup vs baseline: 1.0497x; 1.0347x over previous
//
#include <hip/hip_runtime.h>
#include <hip/hip_bf16.h>
#include <cstddef>

// Problem constants (static shapes from the reference)
#define LQ   17821
#define BS   2
#define MTOK (BS * LQ)       // 35642 token rows
#define CDIM 256
#define NHD  8
#define DHEAD 32
#define DFFN 1024

typedef short bf16x4 __attribute__((ext_vector_type(4)));
typedef short bf16x8 __attribute__((ext_vector_type(8)));
typedef float f32x4  __attribute__((ext_vector_type(4)));
typedef float f32x2  __attribute__((ext_vector_type(2)));

typedef const __attribute__((address_space(1))) unsigned char gcu8;
typedef __attribute__((address_space(3))) unsigned char lu8;

// async global->LDS, 16B per lane, dest = wave-uniform base + lane*16 (linear)
__device__ __forceinline__ void gload16(const void* g, void* l) {
    __builtin_amdgcn_global_load_lds((gcu8*)g, (lu8*)l, 16, 0, 0);
}

// counted VMEM wait (does NOT drain to 0 — loads stay in flight across barriers)
template <int N>
__device__ __forceinline__ void waitvm() {
    asm volatile("s_waitcnt vmcnt(%0)" :: "n"(N) : "memory");
}

// ---------------------------------------------------------------------------
// fp8 e4m3 (OCP) encode/decode helpers — HW path with SW fallback
// ---------------------------------------------------------------------------
__device__ __forceinline__ unsigned char fp8_enc(float f) {
#if __has_builtin(__builtin_amdgcn_cvt_pk_fp8_f32)
    return (unsigned char)(__builtin_amdgcn_cvt_pk_fp8_f32(f, f, 0, false) & 0xff);
#else
    unsigned s = (__float_as_uint(f) >> 31) << 7;
    float af = fabsf(f);
    if (af < 0.0078125f) return (unsigned char)s;   // flush tiny/subnormal
    af = fminf(af, 448.f);
    unsigned b = __float_as_uint(af);
    int e = (int)(b >> 23) - 127 + 7;
    unsigned m = (b >> 20) & 7;
    if (b & 0x80000) { m++; if (m == 8) { m = 0; e++; } }
    if (e < 1) return (unsigned char)s;
    if (e > 15) { e = 15; m = 6; }
    return (unsigned char)(s | ((unsigned)e << 3) | m);
#endif
}

__device__ __forceinline__ float fp8_dec_byte(unsigned x) {
    unsigned s = (x >> 7) & 1, e = (x >> 3) & 15, m = x & 7;
    float v = e ? __uint_as_float(((e + 120u) << 23) | (m << 20))
                : (float)m * 0.001953125f;
    return s ? -v : v;
}

// Decode 2 fp8 bytes (low pair HI=false, high pair HI=true) of a dword.
template <bool HI>
__device__ __forceinline__ f32x2 fp8_dec2(unsigned d) {
#if __has_builtin(__builtin_amdgcn_cvt_pk_f32_fp8)
    return __builtin_amdgcn_cvt_pk_f32_fp8(d, HI);
#else
    f32x2 r;
    r[0] = fp8_dec_byte((d >> (HI ? 16 : 0)) & 0xff);
    r[1] = fp8_dec_byte((d >> (HI ? 24 : 8)) & 0xff);
    return r;
#endif
}

__device__ __forceinline__ ushort bfpack(float f) {
    __hip_bfloat16 h = (__hip_bfloat16)f;
    return *(ushort*)&h;
}

// Stage 8 fp8 bytes (uint2) -> 8 bf16 in LDS
__device__ __forceinline__ void stage_a8(short* p, uint2 d) {
    const f32x2 p0 = fp8_dec2<false>(d.x), p1 = fp8_dec2<true>(d.x);
    const f32x2 p2 = fp8_dec2<false>(d.y), p3 = fp8_dec2<true>(d.y);
    bf16x4 lo, hi;
    lo[0] = (short)bfpack(p0[0]); lo[1] = (short)bfpack(p0[1]);
    lo[2] = (short)bfpack(p1[0]); lo[3] = (short)bfpack(p1[1]);
    hi[0] = (short)bfpack(p2[0]); hi[1] = (short)bfpack(p2[1]);
    hi[2] = (short)bfpack(p3[0]); hi[3] = (short)bfpack(p3[1]);
    ((bf16x4*)p)[0] = lo;
    ((bf16x4*)p)[1] = hi;
}

// ---------------------------------------------------------------------------
// Batched fp32 -> bf16 weight cast; optional per-column scale (norm folding)
// ---------------------------------------------------------------------------
struct CastJobs {
    const float* src[7];
    __hip_bfloat16* dst[7];
    const float* colw[7];   // if non-null: dst = src * colw[i & 255]
    int n[7];
};

__global__ __launch_bounds__(256)
void cast_all(CastJobs j) {
    const int seg = blockIdx.y;
    const int i = blockIdx.x * 256 + threadIdx.x;
    if (i < j.n[seg]) {
        float v = j.src[seg][i];
        if (j.colw[seg]) v *= j.colw[seg][i & 255];
        j.dst[seg][i] = (__hip_bfloat16)v;
    }
}

// ---------------------------------------------------------------------------
// RMSNorm, wave-per-token (64 lanes x float4 = 256 ch), 4 tokens/block.
// ---------------------------------------------------------------------------
template <bool ADD_POS>
__global__ __launch_bounds__(256)
void rmsnorm_kernel(const float* __restrict__ x, const float* __restrict__ pos,
                    const float* __restrict__ w,
                    __hip_bfloat16* __restrict__ outN, __hip_bfloat16* __restrict__ outQ) {
    const int tok = blockIdx.x * 4 + (threadIdx.x >> 6);
    if (tok >= MTOK) return;
    const int lane = threadIdx.x & 63;
    const size_t base = (size_t)tok * CDIM + lane * 4;
    const float4 v = *(const float4*)&x[base];
    float ss = v.x * v.x + v.y * v.y + v.z * v.z + v.w * v.w;
#pragma unroll
    for (int m = 1; m < 64; m <<= 1) ss += __shfl_xor(ss, m, 64);
    const float r = rsqrtf(ss * (1.0f / CDIM) + 1e-6f);
    const float4 wv = *(const float4*)&w[lane * 4];
    const float n0 = v.x * r * wv.x, n1 = v.y * r * wv.y;
    const float n2 = v.z * r * wv.z, n3 = v.w * r * wv.w;
    ushort4 o;
    o.x = bfpack(n0); o.y = bfpack(n1); o.z = bfpack(n2); o.w = bfpack(n3);
    *(ushort4*)&outN[base] = o;
    if (ADD_POS) {
        const float4 p = *(const float4*)&pos[base];
        ushort4 q;
        q.x = bfpack(n0 + p.x); q.y = bfpack(n1 + p.y);
        q.z = bfpack(n2 + p.z); q.w = bfpack(n3 + p.w);
        *(ushort4*)&outQ[base] = q;
    }
}

// ---------------------------------------------------------------------------
// Row RMS scale only: r[m] = rsqrt(mean(x^2)+eps), x bf16. 4 tokens/block.
// ---------------------------------------------------------------------------
__global__ __launch_bounds__(256)
void rowrms_kernel(const __hip_bfloat16* __restrict__ x, float* __restrict__ r) {
    const int tok = blockIdx.x * 4 + (threadIdx.x >> 6);
    if (tok >= MTOK) return;
    const int lane = threadIdx.x & 63;
    const ushort4 u = *(const ushort4*)&x[(size_t)tok * CDIM + lane * 4];
    const float v0 = __uint_as_float((unsigned)u.x << 16);
    const float v1 = __uint_as_float((unsigned)u.y << 16);
    const float v2 = __uint_as_float((unsigned)u.z << 16);
    const float v3 = __uint_as_float((unsigned)u.w << 16);
    float ss = v0 * v0 + v1 * v1 + v2 * v2 + v3 * v3;
#pragma unroll
    for (int m = 1; m < 64; m <<= 1) ss += __shfl_xor(ss, m, 64);
    if (lane == 0) r[tok] = rsqrtf(ss * (1.0f / CDIM) + 1e-6f);
}

// ---------------------------------------------------------------------------
// bf16 MFMA GEMM: C[M,N] = A[M,K] @ W[N,K]^T (+ epilogues), fp32 accumulate.
// 128x128 block tile, templated BK, 4 waves (2x2), wave = 4x4 of 16x16x32.
// Flat grid, n-fastest swizzle: m0 = bid/nsw, n0 = bid%nsw (L2 A-reuse).
// A8: A operand stored fp8 e4m3, decoded to bf16 during LDS staging.
// MODE 0: out = acc + bias1
// MODE 1: value layout write (b, h, q, c), fp8 e4m3
// MODE 2: out = resid_f32 + ls * (acc + bias1)
// MODE 4: out = acc + concat(bias1[0:256], bias2[0:128])[n]   (proj N=384)
// MODE 5: out = resid_bf16 + ls * (acc + bias1), f32 out
// ---------------------------------------------------------------------------
#define GBM 128
#define GBN 128

template <int MODE, int BKT, typename OUTT, bool A8 = false>
__global__ __launch_bounds__(256, 2)
void mfma_gemm(const void* __restrict__ Av,
               const __hip_bfloat16* __restrict__ B1, const float* __restrict__ bias1,
               const float* __restrict__ bias2,
               const float* __restrict__ resid, const __hip_bfloat16* __restrict__ residb,
               const float* __restrict__ ls,
               OUTT* __restrict__ out, int M, int N, int K, int nsw) {
    constexpr int LDKT = BKT + 8;        // +16B pad: 2-way bank alias (free)
    constexpr int CH = BKT / 16;         // staging chunks per thread per matrix
    constexpr int CPR = BKT / 8;         // 8-elem chunks per row

    __shared__ short As[GBM * LDKT];
    __shared__ short Bs[GBN * LDKT];

    const __hip_bfloat16* A = (const __hip_bfloat16*)Av;
    const unsigned char* A8p = (const unsigned char*)Av;

    const int tid = threadIdx.x;
    const int bid = blockIdx.x;
    const int m0 = (bid / nsw) * GBM;
    const int n0 = (bid % nsw) * GBN;
    const int wave = tid >> 6;
    const int lane = tid & 63;
    const int wm = (wave >> 1) * 64;
    const int wn = (wave & 1) * 64;
    const int fr = lane & 15;   // col of C
    const int fq = lane >> 4;   // quad: k = fq*8+j ; C row = fq*4+r

    f32x4 acc[4][4] = {};

    int srow[CH], skc[CH];
#pragma unroll
    for (int cc = 0; cc < CH; ++cc) {
        const int g = tid + cc * 256;
        srow[cc] = g / CPR;
        skc[cc] = (g % CPR) * 8;
    }
    const uint4 zero4 = make_uint4(0, 0, 0, 0);
    const uint2 zero2 = make_uint2(0, 0);

    uint4 ra[CH], rb[CH];
    uint2 ra8[A8 ? CH : 1];
#pragma unroll
    for (int cc = 0; cc < CH; ++cc) {
        const int gm = m0 + srow[cc];
        if constexpr (A8)
            ra8[cc] = (gm < M) ? *(const uint2*)&A8p[(size_t)gm * K + skc[cc]] : zero2;
        else
            ra[cc] = (gm < M) ? *(const uint4*)&A[(size_t)gm * K + skc[cc]] : zero4;
        rb[cc] = *(const uint4*)&B1[(size_t)(n0 + srow[cc]) * K + skc[cc]];
    }

    for (int k0 = 0; k0 < K; k0 += BKT) {
        __syncthreads();
#pragma unroll
        for (int cc = 0; cc < CH; ++cc) {
            short* pa = &As[srow[cc] * LDKT + skc[cc]];
            short* pb = &Bs[srow[cc] * LDKT + skc[cc]];
            if constexpr (A8) {
                stage_a8(pa, ra8[cc]);
            } else {
                union { uint4 u; bf16x4 h[2]; } cv;
                cv.u = ra[cc]; ((bf16x4*)pa)[0] = cv.h[0]; ((bf16x4*)pa)[1] = cv.h[1];
            }
            union { uint4 u; bf16x4 h[2]; } cv;
            cv.u = rb[cc]; ((bf16x4*)pb)[0] = cv.h[0]; ((bf16x4*)pb)[1] = cv.h[1];
        }
        __syncthreads();

        if (k0 + BKT < K) {
            const int kn = k0 + BKT;
#pragma unroll
            for (int cc = 0; cc < CH; ++cc) {
                const int gm = m0 + srow[cc];
                if constexpr (A8)
                    ra8[cc] = (gm < M) ? *(const uint2*)&A8p[(size_t)gm * K + kn + skc[cc]] : zero2;
                else
                    ra[cc] = (gm < M) ? *(const uint4*)&A[(size_t)gm * K + kn + skc[cc]] : zero4;
                rb[cc] = *(const uint4*)&B1[(size_t)(n0 + srow[cc]) * K + kn + skc[cc]];
            }
        }

#pragma unroll
        for (int kk = 0; kk < BKT; kk += 32) {
            const int kq = kk + fq * 8;
            bf16x8 af[4], bfr[4];
#pragma unroll
            for (int i = 0; i < 4; ++i)
                af[i] = *(const bf16x8*)&As[(wm + i * 16 + fr) * LDKT + kq];
#pragma unroll
            for (int j = 0; j < 4; ++j)
                bfr[j] = *(const bf16x8*)&Bs[(wn + j * 16 + fr) * LDKT + kq];
#pragma unroll
            for (int i = 0; i < 4; ++i)
#pragma unroll
                for (int j = 0; j < 4; ++j)
                    acc[i][j] = __builtin_amdgcn_mfma_f32_16x16x32_bf16(af[i], bfr[j], acc[i][j], 0, 0, 0);
        }
    }

#pragma unroll
    for (int i = 0; i < 4; ++i) {
#pragma unroll
        for (int r = 0; r < 4; ++r) {
            const int m = m0 + wm + i * 16 + fq * 4 + r;
            if (m >= M) continue;
#pragma unroll
            for (int j = 0; j < 4; ++j) {
                const int n = n0 + wn + j * 16 + fr;
                float v;
                if constexpr (MODE == 4)
                    v = acc[i][j][r] + ((n < 256) ? bias1[n] : bias2[n - 256]);
                else
                    v = acc[i][j][r] + bias1[n];
                if constexpr (MODE == 0 || MODE == 4) {
                    out[(size_t)m * N + n] = (OUTT)v;
                } else if constexpr (MODE == 1) {
                    const int b = (m >= LQ) ? 1 : 0;
                    const int qi = m - b * LQ;
                    const int h = n >> 5;
                    const int c = n & 31;
                    ((unsigned char*)out)[((size_t)(b * NHD + h) * LQ + qi) * DHEAD + c] = fp8_enc(v);
                } else if constexpr (MODE == 2) {
                    out[(size_t)m * N + n] =
                        (OUTT)(resid[(size_t)m * N + n] + ls[n] * v);
                } else {  // MODE 5: bf16 residual, f32 out
                    const float rx = __uint_as_float(
                        (unsigned)(*(const ushort*)&residb[(size_t)m * N + n]) << 16);
                    out[(size_t)m * N + n] = (OUTT)(rx + ls[n] * v);
                }
            }
        }
    }
}

// ---------------------------------------------------------------------------
// SwiGLU dual GEMM: h = silu(r[m]*(x@W1'^T)+b1) * (r[m]*(x@W2'^T)+b2)
// 128x64 block tile, BK=32, 3-BUFFER DEEP PIPELINE with COUNTED vmcnt (T4):
// loads for tile t+1/t+2 stay in flight across barriers (never drain to 0
// in steady state). Per iteration:
//   waitvm<4*inflight> ; s_barrier      -> all waves' tile-t loads landed
//   compute(t)
//   s_barrier                           -> all waves done reading buf[t%3]
//   stage(t+3) into buf[t%3]            -> WAR-safe overwrite
// Swizzle identical to round-7 (conflict-free verified). LDS 48KB -> 3/CU.
// ---------------------------------------------------------------------------
__global__ __launch_bounds__(256, 3)
void mfma_swiglu(const __hip_bfloat16* __restrict__ A,
                 const __hip_bfloat16* __restrict__ B1, const float* __restrict__ bias1,
                 const __hip_bfloat16* __restrict__ B2, const float* __restrict__ bias2,
                 const float* __restrict__ rrow,
                 unsigned char* __restrict__ out, int M) {
    constexpr int BKT = 32, K = CDIM, N = DFFN, NT = K / BKT;   // NT = 8
    __shared__ short As[3][128 * 32];
    __shared__ short Bs[3][64 * 32];
    __shared__ short Bs2[3][64 * 32];

    const int tid = threadIdx.x;
    const int bid = blockIdx.x;
    const int m0 = (bid >> 4) * 128;     // n-fastest: 16 consecutive blocks share A
    const int n0 = (bid & 15) * 64;
    const int wave = tid >> 6;
    const int lane = tid & 63;
    const int wm = (wave >> 1) * 64;
    const int wn = (wave & 1) * 32;
    const int fr = lane & 15;
    const int fq = lane >> 4;

    f32x4 acc[4][2] = {};
    f32x4 acc2[4][2] = {};

    // staging lane geometry (1024B chunk = 16 rows x 64B):
    // lane L writes LDS slot L*16 -> sources row chunk0+(L>>2),
    // col-chunk (L&3)^((L>>3)&3)
    const int lrow = lane >> 2;                 // 0..15
    const int lcol = (lane & 3) ^ ((lane >> 3) & 3);
    const char* Ab  = (const char*)A;
    const char* B1b = (const char*)B1;
    const char* B2b = (const char*)B2;

    // per-wave: 4 VMEM ops per stage (2 A-chunks + B1 + B2), FIFO order
    auto stage = [&](int b, int k0) {
#pragma unroll
        for (int q = 0; q < 2; ++q) {           // A tile: 8 chunks, 2/wave
            const int c = wave * 2 + q;
            int gm = m0 + c * 16 + lrow;
            gm = (gm < M) ? gm : (M - 1);       // tail clamp (dead rows skipped in epilogue)
            gload16(Ab + ((size_t)gm * K + k0) * 2 + lcol * 16, (char*)As[b] + c * 1024);
        }
        {                                        // B tiles: 4 chunks each, 1/wave
            const size_t rn = (size_t)(n0 + wave * 16 + lrow) * K + k0;
            gload16(B1b + rn * 2 + lcol * 16, (char*)Bs[b] + wave * 1024);
            gload16(B2b + rn * 2 + lcol * 16, (char*)Bs2[b] + wave * 1024);
        }
    };

    stage(0, 0);
    stage(1, BKT);
    stage(2, 2 * BKT);

    const int swz = ((fr >> 1) & 3) << 3;        // read-side XOR, in shorts
    const int co = (fq * 8) ^ swz;               // col short offset within row
#pragma unroll
    for (int t = 0; t < NT; ++t) {
        const int cur = t % 3;
        // Wait own tile-t loads (oldest 4 of the ≤12 outstanding), keep the
        // rest in flight. Then barrier: every wave has passed its wait, so
        // ALL tile-t chunks (written by all 4 waves) are visible.
        if (t < NT - 2)      waitvm<8>();
        else if (t == NT - 2) waitvm<4>();
        else                  waitvm<0>();
        __builtin_amdgcn_s_barrier();
        asm volatile("" ::: "memory");

        bf16x8 af[4], bfr[2], bg[2];
#pragma unroll
        for (int i = 0; i < 4; ++i)
            af[i] = *(const bf16x8*)&As[cur][(wm + i * 16 + fr) * 32 + co];
#pragma unroll
        for (int j = 0; j < 2; ++j) {
            bfr[j] = *(const bf16x8*)&Bs[cur][(wn + j * 16 + fr) * 32 + co];
            bg[j] = *(const bf16x8*)&Bs2[cur][(wn + j * 16 + fr) * 32 + co];
        }
#pragma unroll
        for (int i = 0; i < 4; ++i)
#pragma unroll
            for (int j = 0; j < 2; ++j) {
                acc[i][j] = __builtin_amdgcn_mfma_f32_16x16x32_bf16(af[i], bfr[j], acc[i][j], 0, 0, 0);
                acc2[i][j] = __builtin_amdgcn_mfma_f32_16x16x32_bf16(af[i], bg[j], acc2[i][j], 0, 0, 0);
            }

        asm volatile("" ::: "memory");
        __builtin_amdgcn_s_barrier();            // all waves done reading buf[cur]
        if (t + 3 < NT) stage(cur, (t + 3) * BKT);   // overwrite buf[cur] = buf[(t+3)%3]
    }

#pragma unroll
    for (int i = 0; i < 4; ++i) {
#pragma unroll
        for (int r = 0; r < 4; ++r) {
            const int m = m0 + wm + i * 16 + fq * 4 + r;
            if (m >= M) continue;
            const float rm = rrow[m];
#pragma unroll
            for (int j = 0; j < 2; ++j) {
                const int n = n0 + wn + j * 16 + fr;
                const float v1 = acc[i][j][r] * rm + bias1[n];
                const float v2 = acc2[i][j][r] * rm + bias2[n];
                const float sig = 1.0f / (1.0f + __expf(-v1));
                out[(size_t)m * N + n] = fp8_enc(v1 * sig * v2);
            }
        }
    }
}

// ---------------------------------------------------------------------------
// MSDeformAttn sampling (v4): 4 tokens/block, fp8 value, bf16 proj.
// ---------------------------------------------------------------------------
__global__ __launch_bounds__(256)
void sample_kernel(const unsigned char* __restrict__ value,
                   const ushort* __restrict__ proj,
                   const float* __restrict__ ref,
                   __hip_bfloat16* __restrict__ out) {
    __shared__ float wsm[4][NHD][16];
    __shared__ int2  sTap[4][64][9];

    const int tok0 = blockIdx.x * 4;
    const int t = threadIdx.x;

    if (t < 32) {
        const int tl = t >> 3, h = t & 7;
        const int row = tok0 + tl;
        if (row < MTOK) {
            const ushort* lg = &proj[(size_t)row * 384 + 256 + h * 16];
            float v[16];
            float mx = -3.4e38f;
#pragma unroll
            for (int i = 0; i < 16; ++i) {
                v[i] = __uint_as_float((unsigned)lg[i] << 16);
                mx = fmaxf(mx, v[i]);
            }
            float s = 0.f;
#pragma unroll
            for (int i = 0; i < 16; ++i) { v[i] = __expf(v[i] - mx); s += v[i]; }
            const float inv = 1.0f / s;
#pragma unroll
            for (int i = 0; i < 16; ++i) wsm[tl][h][i] = v[i] * inv;
        }
    }
    __syncthreads();

#pragma unroll
    for (int e = t; e < 512; e += 256) {
        const int tl = e >> 7, hp = e & 127;
        const int row = tok0 + tl;
        if (row < MTOK) {
            const int h = hp >> 4, pt = hp & 15, lv = pt >> 2;
            const int Hs[4] = {100, 50, 25, 13};
            const int Ws[4] = {134, 67, 34, 17};
            const int stt[4] = {0, 13400, 16750, 17600};
            const int H = Hs[lv], W = Ws[lv];
            const float rx = ref[((size_t)row * 4 + lv) * 2 + 0];
            const float ry = ref[((size_t)row * 4 + lv) * 2 + 1];
            const float ox = __uint_as_float((unsigned)proj[(size_t)row * 384 + h * 32 + pt * 2 + 0] << 16);
            const float oy = __uint_as_float((unsigned)proj[(size_t)row * 384 + h * 32 + pt * 2 + 1] << 16);
            const float xf = rx * (float)W + ox - 0.5f;
            const float yf = ry * (float)H + oy - 0.5f;
            const float x0f = floorf(xf), y0f = floorf(yf);
            const float fx = xf - x0f, fy = yf - y0f;
            const int x0 = (int)x0f, y0 = (int)y0f;
            const float aw = wsm[tl][h][pt];
            const int b = (row >= LQ) ? 1 : 0;
            const int base = (b * NHD + h) * LQ + stt[lv];
#pragma unroll
            for (int tap = 0; tap < 4; ++tap) {
                const int dy = tap >> 1, dx = tap & 1;
                const int xi = x0 + dx, yi = y0 + dy;
                const bool valid = (xi >= 0) & (xi < W) & (yi >= 0) & (yi < H);
                const float wgt = (dx ? fx : 1.f - fx) * (dy ? fy : 1.f - fy) * aw;
                sTap[tl][pt * 4 + tap][h] = valid
                    ? make_int2((base + yi * W + xi) * DHEAD, __float_as_int(wgt))
                    : make_int2(0, 0);
            }
        }
    }
    __syncthreads();

    const int tl = t >> 6, lane = t & 63;
    const int row = tok0 + tl;
    if (row >= MTOK) return;
    const int h = lane >> 3, c0 = (lane & 7) * 4;
    const unsigned char* vb = value + c0;
    float a0 = 0.f, a1 = 0.f, a2 = 0.f, a3 = 0.f;
#pragma unroll 8
    for (int i = 0; i < 64; ++i) {
        const int2 tp = sTap[tl][i][h];
        const float w = __int_as_float(tp.y);
        const unsigned d = *(const unsigned*)(vb + (size_t)tp.x);
        const f32x2 lo = fp8_dec2<false>(d);
        const f32x2 hi = fp8_dec2<true>(d);
        a0 = fmaf(w, lo[0], a0);
        a1 = fmaf(w, lo[1], a1);
        a2 = fmaf(w, hi[0], a2);
        a3 = fmaf(w, hi[1], a3);
    }
    ushort4 o;
    o.x = bfpack(a0); o.y = bfpack(a1); o.z = bfpack(a2); o.w = bfpack(a3);
    *(ushort4*)&out[(size_t)row * 256 + h * 32 + c0] = o;
}

// ---------------------------------------------------------------------------
// Workspace (bytes). MCb = 18.25 MB. Peak 7MCb + 2MB = 129.7 MB.
//   [0, MCb)              normed -> sampled
//   [MCb, 2MCb)           q -> x_bf
//   [2MCb, +9.1MB)        value fp8 -> (dead) r_f32 (142 KB)
//   [3MCb, +27.4MB)       proj bf16 -> (dead) h fp8 (36.5 MB) after sampling
//   [7MCb, +2MB)          bf16 weights
// ---------------------------------------------------------------------------
extern "C" void kernel_launch(void* const* d_in, const int* in_sizes, int n_in,
                              void* d_out, int out_size, void* d_ws, size_t ws_size,
                              hipStream_t stream) {
    const float* query      = (const float*)d_in[0];
    const float* query_pos  = (const float*)d_in[1];
    const float* ref        = (const float*)d_in[2];
    const float* norm_attn_w = (const float*)d_in[5];
    const float* Wv   = (const float*)d_in[6];
    const float* bv   = (const float*)d_in[7];
    const float* Woff = (const float*)d_in[8];
    const float* boff = (const float*)d_in[9];
    const float* Waw  = (const float*)d_in[10];
    const float* baw  = (const float*)d_in[11];
    const float* Wo   = (const float*)d_in[12];
    const float* bo   = (const float*)d_in[13];
    const float* ls_attn = (const float*)d_in[14];
    const float* norm_ffn_w = (const float*)d_in[15];
    const float* W1 = (const float*)d_in[16];
    const float* b1 = (const float*)d_in[17];
    const float* W2 = (const float*)d_in[18];
    const float* b2 = (const float*)d_in[19];
    const float* W3 = (const float*)d_in[20];
    const float* b3 = (const float*)d_in[21];
    const float* ls_ffn = (const float*)d_in[22];
    float* out = (float*)d_out;

    char* ws = (char*)d_ws;
    const size_t MCb = (size_t)MTOK * CDIM * 2;   // 18,248,704

    __hip_bfloat16* normed_bf  = (__hip_bfloat16*)(ws);
    __hip_bfloat16* q_bf       = (__hip_bfloat16*)(ws + MCb);
    unsigned char*  value_u8   = (unsigned char*)(ws + 2 * MCb);
    __hip_bfloat16* proj_bf    = (__hip_bfloat16*)(ws + 3 * MCb);
    __hip_bfloat16* sampled_bf = (__hip_bfloat16*)(ws);             // after normed/q dead
    __hip_bfloat16* x_bf       = (__hip_bfloat16*)(ws + MCb);       // after q dead
    float*          r_f        = (float*)(ws + 2 * MCb);            // after value dead
    unsigned char*  h_u8       = (unsigned char*)(ws + 3 * MCb);    // after proj dead
    __hip_bfloat16* wbf        = (__hip_bfloat16*)(ws + 7 * MCb);

    __hip_bfloat16* Wv_bf    = wbf;
    __hip_bfloat16* Wproj_bf = wbf + 65536;    // Woff (256 rows) ++ Waw (128 rows)
    __hip_bfloat16* Wo_bf    = wbf + 163840;
    __hip_bfloat16* W1_bf    = wbf + 229376;   // norm_ffn_w folded
    __hip_bfloat16* W2_bf    = wbf + 491520;   // norm_ffn_w folded
    __hip_bfloat16* W3_bf    = wbf + 753664;

    // 0. all weight casts in one dispatch (W1/W2 get norm_ffn_w column-folded)
    CastJobs cj;
    cj.src[0] = Wv;   cj.dst[0] = Wv_bf;            cj.colw[0] = nullptr; cj.n[0] = 65536;
    cj.src[1] = Woff; cj.dst[1] = Wproj_bf;         cj.colw[1] = nullptr; cj.n[1] = 65536;
    cj.src[2] = Waw;  cj.dst[2] = Wproj_bf + 65536; cj.colw[2] = nullptr; cj.n[2] = 32768;
    cj.src[3] = Wo;   cj.dst[3] = Wo_bf;            cj.colw[3] = nullptr; cj.n[3] = 65536;
    cj.src[4] = W1;   cj.dst[4] = W1_bf;            cj.colw[4] = norm_ffn_w; cj.n[4] = 262144;
    cj.src[5] = W2;   cj.dst[5] = W2_bf;            cj.colw[5] = norm_ffn_w; cj.n[5] = 262144;
    cj.src[6] = W3;   cj.dst[6] = W3_bf;            cj.colw[6] = nullptr; cj.n[6] = 262144;
    cast_all<<<dim3(1024, 7), 256, 0, stream>>>(cj);

    const int gx = (MTOK + GBM - 1) / GBM;   // 279
    const int gr = (MTOK + 3) / 4;           // 8911

    // 1. normed_bf, q_bf = normed + pos
    rmsnorm_kernel<true><<<gr, 256, 0, stream>>>(query, query_pos, norm_attn_w, normed_bf, q_bf);
    // 2. value = normed @ Wv^T + bv -> fp8 (b,h,q,c)
    mfma_gemm<1, 64, unsigned char><<<gx * 2, 256, 0, stream>>>(
        normed_bf, Wv_bf, bv, nullptr, nullptr, nullptr, nullptr, value_u8, MTOK, CDIM, CDIM, 2);
    // 3. proj = q @ [Woff;Waw]^T + [boff;baw] -> bf16 (M,384)
    mfma_gemm<4, 64, __hip_bfloat16><<<gx * 3, 256, 0, stream>>>(
        q_bf, Wproj_bf, boff, baw, nullptr, nullptr, nullptr, proj_bf, MTOK, 384, CDIM, 3);
    // 4. deformable sampling -> sampled_bf
    sample_kernel<<<gr, 256, 0, stream>>>(value_u8, (const ushort*)proj_bf, ref, sampled_bf);
    // 5. x = query + ls_attn * (sampled @ Wo^T + bo) -> bf16
    mfma_gemm<2, 64, __hip_bfloat16><<<gx * 2, 256, 0, stream>>>(
        sampled_bf, Wo_bf, bo, nullptr, query, nullptr, ls_attn, x_bf, MTOK, CDIM, CDIM, 2);
    // 6. r[m] = rsqrt(mean(x^2)+eps)
    rowrms_kernel<<<gr, 256, 0, stream>>>(x_bf, r_f);
    // 7. h = silu(r*(x@W1'^T)+b1) * (r*(x@W2'^T)+b2) -> fp8
    mfma_swiglu<<<gx * 16, 256, 0, stream>>>(
        x_bf, W1_bf, b1, W2_bf, b2, r_f, h_u8, MTOK);
    // 8. out = x + ls_ffn * (h @ W3^T + b3) -> f32 (A is fp8)
    mfma_gemm<5, 64, float, true><<<gx * 2, 256, 0, stream>>>(
        h_u8, W3_bf, b3, nullptr, nullptr, x_bf, ls_ffn, out, MTOK, CDIM, DFFN, 2);
}

// Round 9
// 372.362 us; speedup vs baseline: 1.0553x; 1.0053x over previous
//
#include <hip/hip_runtime.h>
#include <hip/hip_bf16.h>
#include <cstddef>

// Problem constants (static shapes from the reference)
#define LQ   17821
#define BS   2
#define MTOK (BS * LQ)       // 35642 token rows
#define CDIM 256
#define NHD  8
#define DHEAD 32
#define DFFN 1024

typedef short bf16x4 __attribute__((ext_vector_type(4)));
typedef short bf16x8 __attribute__((ext_vector_type(8)));
typedef float f32x4  __attribute__((ext_vector_type(4)));
typedef float f32x2  __attribute__((ext_vector_type(2)));

typedef const __attribute__((address_space(1))) unsigned char gcu8;
typedef __attribute__((address_space(3))) unsigned char lu8;

// async global->LDS, 16B per lane, dest = wave-uniform base + lane*16 (linear)
__device__ __forceinline__ void gload16(const void* g, void* l) {
    __builtin_amdgcn_global_load_lds((gcu8*)g, (lu8*)l, 16, 0, 0);
}

// XCD-aware bijective block remap (T1, m204): HW round-robins blockIdx%8
// across XCDs; this gives each XCD a CONTIGUOUS logical-bid range so blocks
// sharing an A-panel hit the same (non-coherent) per-XCD L2.
__device__ __forceinline__ int xcd_swizzle(int w, int nwg) {
    const int q = nwg >> 3, r = nwg & 7;
    const int x = w & 7, i = w >> 3;
    return (x < r ? x * (q + 1) : r * (q + 1) + (x - r) * q) + i;
}

// ---------------------------------------------------------------------------
// fp8 e4m3 (OCP) encode/decode helpers — HW path with SW fallback
// ---------------------------------------------------------------------------
__device__ __forceinline__ unsigned char fp8_enc(float f) {
#if __has_builtin(__builtin_amdgcn_cvt_pk_fp8_f32)
    return (unsigned char)(__builtin_amdgcn_cvt_pk_fp8_f32(f, f, 0, false) & 0xff);
#else
    unsigned s = (__float_as_uint(f) >> 31) << 7;
    float af = fabsf(f);
    if (af < 0.0078125f) return (unsigned char)s;   // flush tiny/subnormal
    af = fminf(af, 448.f);
    unsigned b = __float_as_uint(af);
    int e = (int)(b >> 23) - 127 + 7;
    unsigned m = (b >> 20) & 7;
    if (b & 0x80000) { m++; if (m == 8) { m = 0; e++; } }
    if (e < 1) return (unsigned char)s;
    if (e > 15) { e = 15; m = 6; }
    return (unsigned char)(s | ((unsigned)e << 3) | m);
#endif
}

__device__ __forceinline__ float fp8_dec_byte(unsigned x) {
    unsigned s = (x >> 7) & 1, e = (x >> 3) & 15, m = x & 7;
    float v = e ? __uint_as_float(((e + 120u) << 23) | (m << 20))
                : (float)m * 0.001953125f;
    return s ? -v : v;
}

// Decode 2 fp8 bytes (low pair HI=false, high pair HI=true) of a dword.
template <bool HI>
__device__ __forceinline__ f32x2 fp8_dec2(unsigned d) {
#if __has_builtin(__builtin_amdgcn_cvt_pk_f32_fp8)
    return __builtin_amdgcn_cvt_pk_f32_fp8(d, HI);
#else
    f32x2 r;
    r[0] = fp8_dec_byte((d >> (HI ? 16 : 0)) & 0xff);
    r[1] = fp8_dec_byte((d >> (HI ? 24 : 8)) & 0xff);
    return r;
#endif
}

__device__ __forceinline__ ushort bfpack(float f) {
    __hip_bfloat16 h = (__hip_bfloat16)f;
    return *(ushort*)&h;
}

// Stage 8 fp8 bytes (uint2) -> 8 bf16 in LDS
__device__ __forceinline__ void stage_a8(short* p, uint2 d) {
    const f32x2 p0 = fp8_dec2<false>(d.x), p1 = fp8_dec2<true>(d.x);
    const f32x2 p2 = fp8_dec2<false>(d.y), p3 = fp8_dec2<true>(d.y);
    bf16x4 lo, hi;
    lo[0] = (short)bfpack(p0[0]); lo[1] = (short)bfpack(p0[1]);
    lo[2] = (short)bfpack(p1[0]); lo[3] = (short)bfpack(p1[1]);
    hi[0] = (short)bfpack(p2[0]); hi[1] = (short)bfpack(p2[1]);
    hi[2] = (short)bfpack(p3[0]); hi[3] = (short)bfpack(p3[1]);
    ((bf16x4*)p)[0] = lo;
    ((bf16x4*)p)[1] = hi;
}

// ---------------------------------------------------------------------------
// Batched fp32 -> bf16 weight cast; optional per-column scale (norm folding)
// ---------------------------------------------------------------------------
struct CastJobs {
    const float* src[7];
    __hip_bfloat16* dst[7];
    const float* colw[7];   // if non-null: dst = src * colw[i & 255]
    int n[7];
};

__global__ __launch_bounds__(256)
void cast_all(CastJobs j) {
    const int seg = blockIdx.y;
    const int i = blockIdx.x * 256 + threadIdx.x;
    if (i < j.n[seg]) {
        float v = j.src[seg][i];
        if (j.colw[seg]) v *= j.colw[seg][i & 255];
        j.dst[seg][i] = (__hip_bfloat16)v;
    }
}

// ---------------------------------------------------------------------------
// RMSNorm, wave-per-token (64 lanes x float4 = 256 ch), 4 tokens/block.
// ---------------------------------------------------------------------------
template <bool ADD_POS>
__global__ __launch_bounds__(256)
void rmsnorm_kernel(const float* __restrict__ x, const float* __restrict__ pos,
                    const float* __restrict__ w,
                    __hip_bfloat16* __restrict__ outN, __hip_bfloat16* __restrict__ outQ) {
    const int tok = blockIdx.x * 4 + (threadIdx.x >> 6);
    if (tok >= MTOK) return;
    const int lane = threadIdx.x & 63;
    const size_t base = (size_t)tok * CDIM + lane * 4;
    const float4 v = *(const float4*)&x[base];
    float ss = v.x * v.x + v.y * v.y + v.z * v.z + v.w * v.w;
#pragma unroll
    for (int m = 1; m < 64; m <<= 1) ss += __shfl_xor(ss, m, 64);
    const float r = rsqrtf(ss * (1.0f / CDIM) + 1e-6f);
    const float4 wv = *(const float4*)&w[lane * 4];
    const float n0 = v.x * r * wv.x, n1 = v.y * r * wv.y;
    const float n2 = v.z * r * wv.z, n3 = v.w * r * wv.w;
    ushort4 o;
    o.x = bfpack(n0); o.y = bfpack(n1); o.z = bfpack(n2); o.w = bfpack(n3);
    *(ushort4*)&outN[base] = o;
    if (ADD_POS) {
        const float4 p = *(const float4*)&pos[base];
        ushort4 q;
        q.x = bfpack(n0 + p.x); q.y = bfpack(n1 + p.y);
        q.z = bfpack(n2 + p.z); q.w = bfpack(n3 + p.w);
        *(ushort4*)&outQ[base] = q;
    }
}

// ---------------------------------------------------------------------------
// Row RMS scale only: r[m] = rsqrt(mean(x^2)+eps), x bf16. 4 tokens/block.
// ---------------------------------------------------------------------------
__global__ __launch_bounds__(256)
void rowrms_kernel(const __hip_bfloat16* __restrict__ x, float* __restrict__ r) {
    const int tok = blockIdx.x * 4 + (threadIdx.x >> 6);
    if (tok >= MTOK) return;
    const int lane = threadIdx.x & 63;
    const ushort4 u = *(const ushort4*)&x[(size_t)tok * CDIM + lane * 4];
    const float v0 = __uint_as_float((unsigned)u.x << 16);
    const float v1 = __uint_as_float((unsigned)u.y << 16);
    const float v2 = __uint_as_float((unsigned)u.z << 16);
    const float v3 = __uint_as_float((unsigned)u.w << 16);
    float ss = v0 * v0 + v1 * v1 + v2 * v2 + v3 * v3;
#pragma unroll
    for (int m = 1; m < 64; m <<= 1) ss += __shfl_xor(ss, m, 64);
    if (lane == 0) r[tok] = rsqrtf(ss * (1.0f / CDIM) + 1e-6f);
}

// ---------------------------------------------------------------------------
// bf16 MFMA GEMM: C[M,N] = A[M,K] @ W[N,K]^T (+ epilogues), fp32 accumulate.
// 128x128 block tile, templated BK, 4 waves (2x2), wave = 4x4 of 16x16x32.
// Flat grid, n-fastest swizzle + XCD-aware bid remap (T1): blocks sharing an
// A-panel land on one XCD's L2.
// A8: A operand stored fp8 e4m3, decoded to bf16 during LDS staging.
// MODE 0: out = acc + bias1
// MODE 1: value layout write (b, h, q, c), fp8 e4m3
// MODE 2: out = resid_f32 + ls * (acc + bias1)
// MODE 4: out = acc + concat(bias1[0:256], bias2[0:128])[n]   (proj N=384)
// MODE 5: out = resid_bf16 + ls * (acc + bias1), f32 out
// ---------------------------------------------------------------------------
#define GBM 128
#define GBN 128

template <int MODE, int BKT, typename OUTT, bool A8 = false>
__global__ __launch_bounds__(256, 2)
void mfma_gemm(const void* __restrict__ Av,
               const __hip_bfloat16* __restrict__ B1, const float* __restrict__ bias1,
               const float* __restrict__ bias2,
               const float* __restrict__ resid, const __hip_bfloat16* __restrict__ residb,
               const float* __restrict__ ls,
               OUTT* __restrict__ out, int M, int N, int K, int nsw) {
    constexpr int LDKT = BKT + 8;        // +16B pad: 2-way bank alias (free)
    constexpr int CH = BKT / 16;         // staging chunks per thread per matrix
    constexpr int CPR = BKT / 8;         // 8-elem chunks per row

    __shared__ short As[GBM * LDKT];
    __shared__ short Bs[GBN * LDKT];

    const __hip_bfloat16* A = (const __hip_bfloat16*)Av;
    const unsigned char* A8p = (const unsigned char*)Av;

    const int tid = threadIdx.x;
    const int bid = xcd_swizzle(blockIdx.x, gridDim.x);
    const int m0 = (bid / nsw) * GBM;
    const int n0 = (bid % nsw) * GBN;
    const int wave = tid >> 6;
    const int lane = tid & 63;
    const int wm = (wave >> 1) * 64;
    const int wn = (wave & 1) * 64;
    const int fr = lane & 15;   // col of C
    const int fq = lane >> 4;   // quad: k = fq*8+j ; C row = fq*4+r

    f32x4 acc[4][4] = {};

    int srow[CH], skc[CH];
#pragma unroll
    for (int cc = 0; cc < CH; ++cc) {
        const int g = tid + cc * 256;
        srow[cc] = g / CPR;
        skc[cc] = (g % CPR) * 8;
    }
    const uint4 zero4 = make_uint4(0, 0, 0, 0);
    const uint2 zero2 = make_uint2(0, 0);

    uint4 ra[CH], rb[CH];
    uint2 ra8[A8 ? CH : 1];
#pragma unroll
    for (int cc = 0; cc < CH; ++cc) {
        const int gm = m0 + srow[cc];
        if constexpr (A8)
            ra8[cc] = (gm < M) ? *(const uint2*)&A8p[(size_t)gm * K + skc[cc]] : zero2;
        else
            ra[cc] = (gm < M) ? *(const uint4*)&A[(size_t)gm * K + skc[cc]] : zero4;
        rb[cc] = *(const uint4*)&B1[(size_t)(n0 + srow[cc]) * K + skc[cc]];
    }

    for (int k0 = 0; k0 < K; k0 += BKT) {
        __syncthreads();
#pragma unroll
        for (int cc = 0; cc < CH; ++cc) {
            short* pa = &As[srow[cc] * LDKT + skc[cc]];
            short* pb = &Bs[srow[cc] * LDKT + skc[cc]];
            if constexpr (A8) {
                stage_a8(pa, ra8[cc]);
            } else {
                union { uint4 u; bf16x4 h[2]; } cv;
                cv.u = ra[cc]; ((bf16x4*)pa)[0] = cv.h[0]; ((bf16x4*)pa)[1] = cv.h[1];
            }
            union { uint4 u; bf16x4 h[2]; } cv;
            cv.u = rb[cc]; ((bf16x4*)pb)[0] = cv.h[0]; ((bf16x4*)pb)[1] = cv.h[1];
        }
        __syncthreads();

        if (k0 + BKT < K) {
            const int kn = k0 + BKT;
#pragma unroll
            for (int cc = 0; cc < CH; ++cc) {
                const int gm = m0 + srow[cc];
                if constexpr (A8)
                    ra8[cc] = (gm < M) ? *(const uint2*)&A8p[(size_t)gm * K + kn + skc[cc]] : zero2;
                else
                    ra[cc] = (gm < M) ? *(const uint4*)&A[(size_t)gm * K + kn + skc[cc]] : zero4;
                rb[cc] = *(const uint4*)&B1[(size_t)(n0 + srow[cc]) * K + kn + skc[cc]];
            }
        }

#pragma unroll
        for (int kk = 0; kk < BKT; kk += 32) {
            const int kq = kk + fq * 8;
            bf16x8 af[4], bfr[4];
#pragma unroll
            for (int i = 0; i < 4; ++i)
                af[i] = *(const bf16x8*)&As[(wm + i * 16 + fr) * LDKT + kq];
#pragma unroll
            for (int j = 0; j < 4; ++j)
                bfr[j] = *(const bf16x8*)&Bs[(wn + j * 16 + fr) * LDKT + kq];
#pragma unroll
            for (int i = 0; i < 4; ++i)
#pragma unroll
                for (int j = 0; j < 4; ++j)
                    acc[i][j] = __builtin_amdgcn_mfma_f32_16x16x32_bf16(af[i], bfr[j], acc[i][j], 0, 0, 0);
        }
    }

#pragma unroll
    for (int i = 0; i < 4; ++i) {
#pragma unroll
        for (int r = 0; r < 4; ++r) {
            const int m = m0 + wm + i * 16 + fq * 4 + r;
            if (m >= M) continue;
#pragma unroll
            for (int j = 0; j < 4; ++j) {
                const int n = n0 + wn + j * 16 + fr;
                float v;
                if constexpr (MODE == 4)
                    v = acc[i][j][r] + ((n < 256) ? bias1[n] : bias2[n - 256]);
                else
                    v = acc[i][j][r] + bias1[n];
                if constexpr (MODE == 0 || MODE == 4) {
                    out[(size_t)m * N + n] = (OUTT)v;
                } else if constexpr (MODE == 1) {
                    const int b = (m >= LQ) ? 1 : 0;
                    const int qi = m - b * LQ;
                    const int h = n >> 5;
                    const int c = n & 31;
                    ((unsigned char*)out)[((size_t)(b * NHD + h) * LQ + qi) * DHEAD + c] = fp8_enc(v);
                } else if constexpr (MODE == 2) {
                    out[(size_t)m * N + n] =
                        (OUTT)(resid[(size_t)m * N + n] + ls[n] * v);
                } else {  // MODE 5: bf16 residual, f32 out
                    const float rx = __uint_as_float(
                        (unsigned)(*(const ushort*)&residb[(size_t)m * N + n]) << 16);
                    out[(size_t)m * N + n] = (OUTT)(rx + ls[n] * v);
                }
            }
        }
    }
}

// ---------------------------------------------------------------------------
// SwiGLU dual GEMM: h = silu(r[m]*(x@W1'^T)+b1) * (r[m]*(x@W2'^T)+b2)
// Round-7 structure (best measured): 128x64 tile, BK=32, double-buffered
// global_load_lds staging (32KB total LDS), XOR-swizzled content,
// + XCD-aware bid remap (T1): the 16 n-blocks sharing an A-panel now land
// on the same XCD's L2 (grid 4464 % 8 == 0 -> simple contiguous split).
// ---------------------------------------------------------------------------
__global__ __launch_bounds__(256, 3)
void mfma_swiglu(const __hip_bfloat16* __restrict__ A,
                 const __hip_bfloat16* __restrict__ B1, const float* __restrict__ bias1,
                 const __hip_bfloat16* __restrict__ B2, const float* __restrict__ bias2,
                 const float* __restrict__ rrow,
                 unsigned char* __restrict__ out, int M) {
    constexpr int BKT = 32, K = CDIM, N = DFFN, NT = K / BKT;   // NT = 8
    __shared__ short As[2][128 * 32];
    __shared__ short Bs[2][64 * 32];
    __shared__ short Bs2[2][64 * 32];

    const int tid = threadIdx.x;
    const int bid = xcd_swizzle(blockIdx.x, gridDim.x);
    const int m0 = (bid >> 4) * 128;     // n-fastest: 16 consecutive blocks share A
    const int n0 = (bid & 15) * 64;
    const int wave = tid >> 6;
    const int lane = tid & 63;
    const int wm = (wave >> 1) * 64;
    const int wn = (wave & 1) * 32;
    const int fr = lane & 15;
    const int fq = lane >> 4;

    f32x4 acc[4][2] = {};
    f32x4 acc2[4][2] = {};

    // staging lane geometry (1024B chunk = 16 rows x 64B):
    // lane L writes LDS slot L*16 -> sources row chunk0+(L>>2),
    // col-chunk (L&3)^((L>>3)&3)
    const int lrow = lane >> 2;                 // 0..15
    const int lcol = (lane & 3) ^ ((lane >> 3) & 3);
    const char* Ab  = (const char*)A;
    const char* B1b = (const char*)B1;
    const char* B2b = (const char*)B2;

    auto stage = [&](int b, int k0) {
#pragma unroll
        for (int q = 0; q < 2; ++q) {           // A tile: 8 chunks, 2/wave
            const int c = wave * 2 + q;
            int gm = m0 + c * 16 + lrow;
            gm = (gm < M) ? gm : (M - 1);       // tail clamp (dead rows skipped in epilogue)
            gload16(Ab + ((size_t)gm * K + k0) * 2 + lcol * 16, (char*)As[b] + c * 1024);
        }
        {                                        // B tiles: 4 chunks each, 1/wave
            const size_t rn = (size_t)(n0 + wave * 16 + lrow) * K + k0;
            gload16(B1b + rn * 2 + lcol * 16, (char*)Bs[b] + wave * 1024);
            gload16(B2b + rn * 2 + lcol * 16, (char*)Bs2[b] + wave * 1024);
        }
    };

    stage(0, 0);

    const int swz = ((fr >> 1) & 3) << 3;        // read-side XOR, in shorts
    const int co = (fq * 8) ^ swz;               // col short offset within row
#pragma unroll
    for (int t = 0; t < NT; ++t) {
        const int cur = t & 1;
        // barrier's implicit s_waitcnt vmcnt(0) drains buf[cur]'s loads
        // (issued last iteration, overlapped with last iteration's MFMAs)
        // and orders all waves past their previous compute (WAR for nxt).
        __syncthreads();
        if (t + 1 < NT) stage(cur ^ 1, (t + 1) * BKT);

        bf16x8 af[4], bfr[2], bg[2];
#pragma unroll
        for (int i = 0; i < 4; ++i)
            af[i] = *(const bf16x8*)&As[cur][(wm + i * 16 + fr) * 32 + co];
#pragma unroll
        for (int j = 0; j < 2; ++j) {
            bfr[j] = *(const bf16x8*)&Bs[cur][(wn + j * 16 + fr) * 32 + co];
            bg[j] = *(const bf16x8*)&Bs2[cur][(wn + j * 16 + fr) * 32 + co];
        }
#pragma unroll
        for (int i = 0; i < 4; ++i)
#pragma unroll
            for (int j = 0; j < 2; ++j) {
                acc[i][j] = __builtin_amdgcn_mfma_f32_16x16x32_bf16(af[i], bfr[j], acc[i][j], 0, 0, 0);
                acc2[i][j] = __builtin_amdgcn_mfma_f32_16x16x32_bf16(af[i], bg[j], acc2[i][j], 0, 0, 0);
            }
    }

#pragma unroll
    for (int i = 0; i < 4; ++i) {
#pragma unroll
        for (int r = 0; r < 4; ++r) {
            const int m = m0 + wm + i * 16 + fq * 4 + r;
            if (m >= M) continue;
            const float rm = rrow[m];
#pragma unroll
            for (int j = 0; j < 2; ++j) {
                const int n = n0 + wn + j * 16 + fr;
                const float v1 = acc[i][j][r] * rm + bias1[n];
                const float v2 = acc2[i][j][r] * rm + bias2[n];
                const float sig = 1.0f / (1.0f + __expf(-v1));
                out[(size_t)m * N + n] = fp8_enc(v1 * sig * v2);
            }
        }
    }
}

// ---------------------------------------------------------------------------
// MSDeformAttn sampling (v4): 4 tokens/block, fp8 value, bf16 proj.
// ---------------------------------------------------------------------------
__global__ __launch_bounds__(256)
void sample_kernel(const unsigned char* __restrict__ value,
                   const ushort* __restrict__ proj,
                   const float* __restrict__ ref,
                   __hip_bfloat16* __restrict__ out) {
    __shared__ float wsm[4][NHD][16];
    __shared__ int2  sTap[4][64][9];

    const int tok0 = blockIdx.x * 4;
    const int t = threadIdx.x;

    if (t < 32) {
        const int tl = t >> 3, h = t & 7;
        const int row = tok0 + tl;
        if (row < MTOK) {
            const ushort* lg = &proj[(size_t)row * 384 + 256 + h * 16];
            float v[16];
            float mx = -3.4e38f;
#pragma unroll
            for (int i = 0; i < 16; ++i) {
                v[i] = __uint_as_float((unsigned)lg[i] << 16);
                mx = fmaxf(mx, v[i]);
            }
            float s = 0.f;
#pragma unroll
            for (int i = 0; i < 16; ++i) { v[i] = __expf(v[i] - mx); s += v[i]; }
            const float inv = 1.0f / s;
#pragma unroll
            for (int i = 0; i < 16; ++i) wsm[tl][h][i] = v[i] * inv;
        }
    }
    __syncthreads();

#pragma unroll
    for (int e = t; e < 512; e += 256) {
        const int tl = e >> 7, hp = e & 127;
        const int row = tok0 + tl;
        if (row < MTOK) {
            const int h = hp >> 4, pt = hp & 15, lv = pt >> 2;
            const int Hs[4] = {100, 50, 25, 13};
            const int Ws[4] = {134, 67, 34, 17};
            const int stt[4] = {0, 13400, 16750, 17600};
            const int H = Hs[lv], W = Ws[lv];
            const float rx = ref[((size_t)row * 4 + lv) * 2 + 0];
            const float ry = ref[((size_t)row * 4 + lv) * 2 + 1];
            const float ox = __uint_as_float((unsigned)proj[(size_t)row * 384 + h * 32 + pt * 2 + 0] << 16);
            const float oy = __uint_as_float((unsigned)proj[(size_t)row * 384 + h * 32 + pt * 2 + 1] << 16);
            const float xf = rx * (float)W + ox - 0.5f;
            const float yf = ry * (float)H + oy - 0.5f;
            const float x0f = floorf(xf), y0f = floorf(yf);
            const float fx = xf - x0f, fy = yf - y0f;
            const int x0 = (int)x0f, y0 = (int)y0f;
            const float aw = wsm[tl][h][pt];
            const int b = (row >= LQ) ? 1 : 0;
            const int base = (b * NHD + h) * LQ + stt[lv];
#pragma unroll
            for (int tap = 0; tap < 4; ++tap) {
                const int dy = tap >> 1, dx = tap & 1;
                const int xi = x0 + dx, yi = y0 + dy;
                const bool valid = (xi >= 0) & (xi < W) & (yi >= 0) & (yi < H);
                const float wgt = (dx ? fx : 1.f - fx) * (dy ? fy : 1.f - fy) * aw;
                sTap[tl][pt * 4 + tap][h] = valid
                    ? make_int2((base + yi * W + xi) * DHEAD, __float_as_int(wgt))
                    : make_int2(0, 0);
            }
        }
    }
    __syncthreads();

    const int tl = t >> 6, lane = t & 63;
    const int row = tok0 + tl;
    if (row >= MTOK) return;
    const int h = lane >> 3, c0 = (lane & 7) * 4;
    const unsigned char* vb = value + c0;
    float a0 = 0.f, a1 = 0.f, a2 = 0.f, a3 = 0.f;
#pragma unroll 8
    for (int i = 0; i < 64; ++i) {
        const int2 tp = sTap[tl][i][h];
        const float w = __int_as_float(tp.y);
        const unsigned d = *(const unsigned*)(vb + (size_t)tp.x);
        const f32x2 lo = fp8_dec2<false>(d);
        const f32x2 hi = fp8_dec2<true>(d);
        a0 = fmaf(w, lo[0], a0);
        a1 = fmaf(w, lo[1], a1);
        a2 = fmaf(w, hi[0], a2);
        a3 = fmaf(w, hi[1], a3);
    }
    ushort4 o;
    o.x = bfpack(a0); o.y = bfpack(a1); o.z = bfpack(a2); o.w = bfpack(a3);
    *(ushort4*)&out[(size_t)row * 256 + h * 32 + c0] = o;
}

// ---------------------------------------------------------------------------
// Workspace (bytes). MCb = 18.25 MB. Peak 7MCb + 2MB = 129.7 MB.
//   [0, MCb)              normed -> sampled
//   [MCb, 2MCb)           q -> x_bf
//   [2MCb, +9.1MB)        value fp8 -> (dead) r_f32 (142 KB)
//   [3MCb, +27.4MB)       proj bf16 -> (dead) h fp8 (36.5 MB) after sampling
//   [7MCb, +2MB)          bf16 weights
// ---------------------------------------------------------------------------
extern "C" void kernel_launch(void* const* d_in, const int* in_sizes, int n_in,
                              void* d_out, int out_size, void* d_ws, size_t ws_size,
                              hipStream_t stream) {
    const float* query      = (const float*)d_in[0];
    const float* query_pos  = (const float*)d_in[1];
    const float* ref        = (const float*)d_in[2];
    const float* norm_attn_w = (const float*)d_in[5];
    const float* Wv   = (const float*)d_in[6];
    const float* bv   = (const float*)d_in[7];
    const float* Woff = (const float*)d_in[8];
    const float* boff = (const float*)d_in[9];
    const float* Waw  = (const float*)d_in[10];
    const float* baw  = (const float*)d_in[11];
    const float* Wo   = (const float*)d_in[12];
    const float* bo   = (const float*)d_in[13];
    const float* ls_attn = (const float*)d_in[14];
    const float* norm_ffn_w = (const float*)d_in[15];
    const float* W1 = (const float*)d_in[16];
    const float* b1 = (const float*)d_in[17];
    const float* W2 = (const float*)d_in[18];
    const float* b2 = (const float*)d_in[19];
    const float* W3 = (const float*)d_in[20];
    const float* b3 = (const float*)d_in[21];
    const float* ls_ffn = (const float*)d_in[22];
    float* out = (float*)d_out;

    char* ws = (char*)d_ws;
    const size_t MCb = (size_t)MTOK * CDIM * 2;   // 18,248,704

    __hip_bfloat16* normed_bf  = (__hip_bfloat16*)(ws);
    __hip_bfloat16* q_bf       = (__hip_bfloat16*)(ws + MCb);
    unsigned char*  value_u8   = (unsigned char*)(ws + 2 * MCb);
    __hip_bfloat16* proj_bf    = (__hip_bfloat16*)(ws + 3 * MCb);
    __hip_bfloat16* sampled_bf = (__hip_bfloat16*)(ws);             // after normed/q dead
    __hip_bfloat16* x_bf       = (__hip_bfloat16*)(ws + MCb);       // after q dead
    float*          r_f        = (float*)(ws + 2 * MCb);            // after value dead
    unsigned char*  h_u8       = (unsigned char*)(ws + 3 * MCb);    // after proj dead
    __hip_bfloat16* wbf        = (__hip_bfloat16*)(ws + 7 * MCb);

    __hip_bfloat16* Wv_bf    = wbf;
    __hip_bfloat16* Wproj_bf = wbf + 65536;    // Woff (256 rows) ++ Waw (128 rows)
    __hip_bfloat16* Wo_bf    = wbf + 163840;
    __hip_bfloat16* W1_bf    = wbf + 229376;   // norm_ffn_w folded
    __hip_bfloat16* W2_bf    = wbf + 491520;   // norm_ffn_w folded
    __hip_bfloat16* W3_bf    = wbf + 753664;

    // 0. all weight casts in one dispatch (W1/W2 get norm_ffn_w column-folded)
    CastJobs cj;
    cj.src[0] = Wv;   cj.dst[0] = Wv_bf;            cj.colw[0] = nullptr; cj.n[0] = 65536;
    cj.src[1] = Woff; cj.dst[1] = Wproj_bf;         cj.colw[1] = nullptr; cj.n[1] = 65536;
    cj.src[2] = Waw;  cj.dst[2] = Wproj_bf + 65536; cj.colw[2] = nullptr; cj.n[2] = 32768;
    cj.src[3] = Wo;   cj.dst[3] = Wo_bf;            cj.colw[3] = nullptr; cj.n[3] = 65536;
    cj.src[4] = W1;   cj.dst[4] = W1_bf;            cj.colw[4] = norm_ffn_w; cj.n[4] = 262144;
    cj.src[5] = W2;   cj.dst[5] = W2_bf;            cj.colw[5] = norm_ffn_w; cj.n[5] = 262144;
    cj.src[6] = W3;   cj.dst[6] = W3_bf;            cj.colw[6] = nullptr; cj.n[6] = 262144;
    cast_all<<<dim3(1024, 7), 256, 0, stream>>>(cj);

    const int gx = (MTOK + GBM - 1) / GBM;   // 279
    const int gr = (MTOK + 3) / 4;           // 8911

    // 1. normed_bf, q_bf = normed + pos
    rmsnorm_kernel<true><<<gr, 256, 0, stream>>>(query, query_pos, norm_attn_w, normed_bf, q_bf);
    // 2. value = normed @ Wv^T + bv -> fp8 (b,h,q,c)
    mfma_gemm<1, 64, unsigned char><<<gx * 2, 256, 0, stream>>>(
        normed_bf, Wv_bf, bv, nullptr, nullptr, nullptr, nullptr, value_u8, MTOK, CDIM, CDIM, 2);
    // 3. proj = q @ [Woff;Waw]^T + [boff;baw] -> bf16 (M,384)
    mfma_gemm<4, 64, __hip_bfloat16><<<gx * 3, 256, 0, stream>>>(
        q_bf, Wproj_bf, boff, baw, nullptr, nullptr, nullptr, proj_bf, MTOK, 384, CDIM, 3);
    // 4. deformable sampling -> sampled_bf
    sample_kernel<<<gr, 256, 0, stream>>>(value_u8, (const ushort*)proj_bf, ref, sampled_bf);
    // 5. x = query + ls_attn * (sampled @ Wo^T + bo) -> bf16
    mfma_gemm<2, 64, __hip_bfloat16><<<gx * 2, 256, 0, stream>>>(
        sampled_bf, Wo_bf, bo, nullptr, query, nullptr, ls_attn, x_bf, MTOK, CDIM, CDIM, 2);
    // 6. r[m] = rsqrt(mean(x^2)+eps)
    rowrms_kernel<<<gr, 256, 0, stream>>>(x_bf, r_f);
    // 7. h = silu(r*(x@W1'^T)+b1) * (r*(x@W2'^T)+b2) -> fp8
    mfma_swiglu<<<gx * 16, 256, 0, stream>>>(
        x_bf, W1_bf, b1, W2_bf, b2, r_f, h_u8, MTOK);
    // 8. out = x + ls_ffn * (h @ W3^T + b3) -> f32 (A is fp8)
    mfma_gemm<5, 64, float, true><<<gx * 2, 256, 0, stream>>>(
        h_u8, W3_bf, b3, nullptr, nullptr, x_bf, ls_ffn, out, MTOK, CDIM, DFFN, 2);
}